// Round 7
// baseline (421.263 us; speedup 1.0000x reference)
//
#include <hip/hip_runtime.h>
#include <hip/hip_bf16.h>
#include <math.h>
#include <string.h>

#define N_NODES 50000
#define N_EDGES 800000
#define NH 4

typedef unsigned int u32;
typedef unsigned short u16;
typedef __attribute__((ext_vector_type(8))) short bf16x8;
typedef __attribute__((ext_vector_type(4))) float f32x4;

__device__ __forceinline__ u32 pack_bf2(float a, float b) {
    __hip_bfloat162 h2 = __float22bfloat162_rn(make_float2(a, b));
    u32 r;
    memcpy(&r, &h2, 4);
    return r;
}
__device__ __forceinline__ float2 bf2_to_f2(u32 u) {
    return make_float2(__uint_as_float(u << 16), __uint_as_float(u & 0xffff0000u));
}
__device__ __forceinline__ short bf16r(float f) {
    __hip_bfloat16 h = __float2bfloat16(f);
    short s;
    memcpy(&s, &h, 2);
    return s;
}
__device__ __forceinline__ float selH(float4 av, int h) {
    return h == 0 ? av.x : (h == 1 ? av.y : (h == 2 ? av.z : av.w));
}

// ---------------- CSR build ----------------

__global__ void k_hist(const int* __restrict__ dst, int* __restrict__ deg) {
    int i = blockIdx.x * 256 + threadIdx.x;
    if (i < N_EDGES) atomicAdd(&deg[dst[i]], 1);
}

__global__ __launch_bounds__(1024) void k_scan1(const int* __restrict__ deg,
                                                int* __restrict__ offs,
                                                int* __restrict__ bsum) {
    __shared__ int tmp[1024];
    int b = blockIdx.x, t = threadIdx.x;
    int i = b * 1024 + t;
    int v = (i < N_NODES) ? deg[i] : 0;
    tmp[t] = v;
    __syncthreads();
    for (int off = 1; off < 1024; off <<= 1) {
        int add = (t >= off) ? tmp[t - off] : 0;
        __syncthreads();
        tmp[t] += add;
        __syncthreads();
    }
    if (i < N_NODES) offs[i] = tmp[t] - v;
    if (t == 1023) bsum[b] = tmp[t];
}

__global__ void k_scan2(int* __restrict__ bsum, int nb) {
    if (blockIdx.x == 0 && threadIdx.x == 0) {
        int run = 0;
        for (int b = 0; b < nb; ++b) { int v = bsum[b]; bsum[b] = run; run += v; }
    }
}

__global__ __launch_bounds__(1024) void k_scan3(int* __restrict__ offs,
                                                const int* __restrict__ bsum,
                                                int* __restrict__ cursor) {
    int b = blockIdx.x, t = threadIdx.x;
    int i = b * 1024 + t;
    if (i < N_NODES) {
        int o = offs[i] + bsum[b];
        offs[i] = o;
        cursor[i] = o;
    }
    if (b == 0 && t == 0) offs[N_NODES] = N_EDGES;
}

__global__ void k_scatter(const int* __restrict__ src, const int* __restrict__ dst,
                          int* __restrict__ cursor, int* __restrict__ csrc) {
    int i = blockIdx.x * 256 + threadIdx.x;
    if (i < N_EDGES) {
        int p = atomicAdd(&cursor[dst[i]], 1);
        csrc[p] = src[i];
    }
}

// ---------------- W pre-pack into MFMA B-fragment layout ----------------
template <int K, int NOUT, int NP>
__global__ void prep_w(const float* __restrict__ W, u16* __restrict__ Wp) {
    constexpr int NT = NP / 16;
    int idx = blockIdx.x * 256 + threadIdx.x;
    int total = (K / 32) * NT * 64 * 8;
    if (idx >= total) return;
    int j = idx & 7;
    int lane = (idx >> 3) & 63;
    int rest = idx >> 9;
    int nt = rest % NT;
    int kt = rest / NT;
    int k = kt * 32 + (lane >> 4) * 8 + j;
    int col = nt * 16 + (lane & 15);
    float v = (col < NOUT) ? W[(size_t)k * NOUT + col] : 0.f;
    Wp[idx] = (u16)bf16r(v);
}

// ---------------- MFMA GEMM: feat(bf16,[N,NP]) = A @ W (+fused attn dots) ----------------
template <int K, int NOUT, int NP, bool AF32, bool DOTS>
__global__ __launch_bounds__(256) void gemm_mfma(const void* __restrict__ Av,
                                                 const u16* __restrict__ Wp,
                                                 u16* __restrict__ feat,
                                                 const float* __restrict__ al,
                                                 const float* __restrict__ ar,
                                                 float* __restrict__ el,
                                                 float* __restrict__ er) {
    constexpr int NT = NP / 16;
    constexpr int KT = K / 32;
    int w = threadIdx.x >> 6, l = threadIdx.x & 63;
    int tile_m0 = blockIdx.x * 64 + w * 16;
    int c15 = l & 15;
    int rowA = tile_m0 + c15;
    if (rowA >= N_NODES) rowA = N_NODES - 1;
    int g = l >> 4;

    f32x4 acc[NT];
#pragma unroll
    for (int nt = 0; nt < NT; ++nt) acc[nt] = (f32x4){0.f, 0.f, 0.f, 0.f};

    for (int kt = 0; kt < KT; ++kt) {
        bf16x8 a;
        if constexpr (AF32) {
            const float* ap = (const float*)Av + (size_t)rowA * K + kt * 32 + g * 8;
            float4 f0 = *reinterpret_cast<const float4*>(ap);
            float4 f1 = *reinterpret_cast<const float4*>(ap + 4);
            a[0] = bf16r(f0.x); a[1] = bf16r(f0.y); a[2] = bf16r(f0.z); a[3] = bf16r(f0.w);
            a[4] = bf16r(f1.x); a[5] = bf16r(f1.y); a[6] = bf16r(f1.z); a[7] = bf16r(f1.w);
        } else {
            a = *reinterpret_cast<const bf16x8*>((const u16*)Av + (size_t)rowA * K + kt * 32 + g * 8);
        }
        const u16* wp = Wp + ((size_t)kt * NT) * 512 + (size_t)l * 8;
#pragma unroll
        for (int nt = 0; nt < NT; ++nt) {
            bf16x8 b = *reinterpret_cast<const bf16x8*>(wp + nt * 512);
            acc[nt] = __builtin_amdgcn_mfma_f32_16x16x32_bf16(a, b, acc[nt], 0, 0, 0);
        }
    }

    int rowD0 = tile_m0 + g * 4;
#pragma unroll
    for (int nt = 0; nt < NT; ++nt) {
        int col = nt * 16 + c15;
#pragma unroll
        for (int r = 0; r < 4; ++r) {
            int row = rowD0 + r;
            if (row < N_NODES)
                feat[(size_t)row * NP + col] = (u16)bf16r(acc[nt][r]);  // pad cols: Wp=0 -> acc=0
        }
    }

    if constexpr (DOTS) {
        float alv[NT], arv[NT];
#pragma unroll
        for (int nt = 0; nt < NT; ++nt) {
            alv[nt] = al[nt * 16 + c15];
            arv[nt] = ar[nt * 16 + c15];
        }
#pragma unroll
        for (int r = 0; r < 4; ++r) {
            float hlv[NH] = {0.f, 0.f, 0.f, 0.f};
            float hrv[NH] = {0.f, 0.f, 0.f, 0.f};
#pragma unroll
            for (int nt = 0; nt < NT; ++nt) {
                constexpr int NTH = NT / NH;
                int h = nt / NTH;
                hlv[h] = fmaf(acc[nt][r], alv[nt], hlv[h]);
                hrv[h] = fmaf(acc[nt][r], arv[nt], hrv[h]);
            }
#pragma unroll
            for (int o = 1; o < 16; o <<= 1) {
#pragma unroll
                for (int j = 0; j < NH; ++j) {
                    hlv[j] += __shfl_xor(hlv[j], o);
                    hrv[j] += __shfl_xor(hrv[j], o);
                }
            }
            int row = rowD0 + r;
            if (c15 == 0 && row < N_NODES) {
                *reinterpret_cast<float4*>(el + (size_t)row * NH) =
                    make_float4(hlv[0], hlv[1], hlv[2], hlv[3]);
                *reinterpret_cast<float4*>(er + (size_t)row * NH) =
                    make_float4(hrv[0], hrv[1], hrv[2], hrv[3]);
            }
        }
    }
}

// ---------------- attention dots (layer 3 only) ----------------
template <int DH, int STRIDE>
__global__ __launch_bounds__(256) void attn_dots(const u16* __restrict__ feat,
                                                 const float* __restrict__ al,
                                                 const float* __restrict__ ar,
                                                 float* __restrict__ el,
                                                 float* __restrict__ er) {
    int wave = threadIdx.x >> 6, lane = threadIdx.x & 63;
    int n = blockIdx.x * 4 + wave;
    int h = lane >> 4, t = lane & 15;
    const u16* f = feat + (size_t)n * STRIDE + h * DH;
    const float* alh = al + h * DH;
    const float* arh = ar + h * DH;
    float sl = 0.f, sr = 0.f;
#pragma unroll
    for (int d0 = 0; d0 < DH; d0 += 16) {
        int d = d0 + t;
        if (d < DH) {
            float fv = __uint_as_float(((u32)f[d]) << 16);
            sl = fmaf(fv, alh[d], sl);
            sr = fmaf(fv, arh[d], sr);
        }
    }
#pragma unroll
    for (int o = 1; o < 16; o <<= 1) {
        sl += __shfl_xor(sl, o);
        sr += __shfl_xor(sr, o);
    }
    if (t == 0) { el[n * NH + h] = sl; er[n * NH + h] = sr; }
}

// ---------------- per-node segment softmax -> normalized alpha[E][4] ----------------
__device__ __forceinline__ float wred_max(float v) {
#pragma unroll
    for (int o = 32; o > 0; o >>= 1) v = fmaxf(v, __shfl_xor(v, o));
    return v;
}
__device__ __forceinline__ float wred_sum(float v) {
#pragma unroll
    for (int o = 32; o > 0; o >>= 1) v += __shfl_xor(v, o);
    return v;
}

__global__ __launch_bounds__(256) void softmax_alpha(const float* __restrict__ el,
                                                     const float* __restrict__ er,
                                                     const int* __restrict__ offs,
                                                     const int* __restrict__ csrc,
                                                     float* __restrict__ alpha) {
    const float NEG = -__builtin_inff();
    int wave = threadIdx.x >> 6, lane = threadIdx.x & 63;
    int n = blockIdx.x * 4 + wave;
    int i0 = offs[n], i1 = offs[n + 1];
    if (i0 >= i1) return;
    float4 erv = *reinterpret_cast<const float4*>(er + (size_t)n * NH);

    if (i1 - i0 <= 64) {
        int i = i0 + lane;
        bool act = i < i1;
        int src = act ? csrc[i] : 0;
        float4 elv = make_float4(0.f, 0.f, 0.f, 0.f);
        if (act) elv = *reinterpret_cast<const float4*>(el + (size_t)src * NH);
        float e0 = elv.x + erv.x; e0 = e0 >= 0.f ? e0 : 0.2f * e0;
        float e1 = elv.y + erv.y; e1 = e1 >= 0.f ? e1 : 0.2f * e1;
        float e2 = elv.z + erv.z; e2 = e2 >= 0.f ? e2 : 0.2f * e2;
        float e3 = elv.w + erv.w; e3 = e3 >= 0.f ? e3 : 0.2f * e3;
        if (!act) { e0 = NEG; e1 = NEG; e2 = NEG; e3 = NEG; }
        float m0 = wred_max(e0), m1 = wred_max(e1), m2 = wred_max(e2), m3 = wred_max(e3);
        float p0 = act ? __expf(e0 - m0) : 0.f;
        float p1 = act ? __expf(e1 - m1) : 0.f;
        float p2 = act ? __expf(e2 - m2) : 0.f;
        float p3 = act ? __expf(e3 - m3) : 0.f;
        float s0 = wred_sum(p0), s1 = wred_sum(p1), s2 = wred_sum(p2), s3 = wred_sum(p3);
        if (act) {
            float4 a = make_float4(p0 / s0, p1 / s1, p2 / s2, p3 / s3);
            *reinterpret_cast<float4*>(alpha + (size_t)i * NH) = a;
        }
        return;
    }

    float m0 = NEG, m1 = NEG, m2 = NEG, m3 = NEG;
    float s0 = 0.f, s1 = 0.f, s2 = 0.f, s3 = 0.f;
    for (int base = i0; base < i1; base += 64) {
        int i = base + lane;
        bool act = i < i1;
        int src = act ? csrc[i] : 0;
        float4 elv = make_float4(0.f, 0.f, 0.f, 0.f);
        if (act) elv = *reinterpret_cast<const float4*>(el + (size_t)src * NH);
        float e0 = elv.x + erv.x; e0 = e0 >= 0.f ? e0 : 0.2f * e0;
        float e1 = elv.y + erv.y; e1 = e1 >= 0.f ? e1 : 0.2f * e1;
        float e2 = elv.z + erv.z; e2 = e2 >= 0.f ? e2 : 0.2f * e2;
        float e3 = elv.w + erv.w; e3 = e3 >= 0.f ? e3 : 0.2f * e3;
        if (!act) { e0 = NEG; e1 = NEG; e2 = NEG; e3 = NEG; }
        float c0 = wred_max(e0), c1 = wred_max(e1), c2 = wred_max(e2), c3 = wred_max(e3);
        float nm0 = fmaxf(m0, c0), nm1 = fmaxf(m1, c1), nm2 = fmaxf(m2, c2), nm3 = fmaxf(m3, c3);
        float p0 = act ? __expf(e0 - nm0) : 0.f;
        float p1 = act ? __expf(e1 - nm1) : 0.f;
        float p2 = act ? __expf(e2 - nm2) : 0.f;
        float p3 = act ? __expf(e3 - nm3) : 0.f;
        float S0 = wred_sum(p0), S1 = wred_sum(p1), S2 = wred_sum(p2), S3 = wred_sum(p3);
        s0 = s0 * __expf(m0 - nm0) + S0; m0 = nm0;
        s1 = s1 * __expf(m1 - nm1) + S1; m1 = nm1;
        s2 = s2 * __expf(m2 - nm2) + S2; m2 = nm2;
        s3 = s3 * __expf(m3 - nm3) + S3; m3 = nm3;
    }
    float v0 = 1.f / s0, v1 = 1.f / s1, v2 = 1.f / s2, v3 = 1.f / s3;
    for (int base = i0; base < i1; base += 64) {
        int i = base + lane;
        bool act = i < i1;
        int src = act ? csrc[i] : 0;
        float4 elv = make_float4(0.f, 0.f, 0.f, 0.f);
        if (act) elv = *reinterpret_cast<const float4*>(el + (size_t)src * NH);
        float e0 = elv.x + erv.x; e0 = e0 >= 0.f ? e0 : 0.2f * e0;
        float e1 = elv.y + erv.y; e1 = e1 >= 0.f ? e1 : 0.2f * e1;
        float e2 = elv.z + erv.z; e2 = e2 >= 0.f ? e2 : 0.2f * e2;
        float e3 = elv.w + erv.w; e3 = e3 >= 0.f ? e3 : 0.2f * e3;
        if (act) {
            float4 a = make_float4(__expf(e0 - m0) * v0, __expf(e1 - m1) * v1,
                                   __expf(e2 - m2) * v2, __expf(e3 - m3) * v3);
            *reinterpret_cast<float4*>(alpha + (size_t)i * NH) = a;
        }
    }
}

// ---------------- aggregation L1-2: edge-cooperative, 16 lanes/row ----------------
// lane: sub=lane>>4 (edge within group of 4), sl=lane&15 (16B col slice).
__global__ __launch_bounds__(256) void gat_agg128(const u16* __restrict__ feat,
                                                  const float* __restrict__ alpha,
                                                  const int* __restrict__ offs,
                                                  const int* __restrict__ csrc,
                                                  u16* __restrict__ out) {
    int wave = threadIdx.x >> 6;
    int lane = threadIdx.x & 63;
    int n = blockIdx.x * 4 + wave;
    int sub = lane >> 4, sl = lane & 15;
    int colbase = sl * 8;
    int h = sl >> 2;
    int i0 = offs[n], i1 = offs[n + 1];
    float acc[8] = {0.f, 0.f, 0.f, 0.f, 0.f, 0.f, 0.f, 0.f};

    for (int i = i0; i < i1; i += 8) {
#pragma unroll
        for (int u = 0; u < 2; ++u) {
            int e = i + u * 4 + sub;
            bool valid = e < i1;
            int s = valid ? csrc[e] : 0;
            float a = valid ? alpha[(size_t)e * NH + h] : 0.f;
            uint4 q = *reinterpret_cast<const uint4*>(feat + (size_t)s * 128 + colbase);
            float2 v0 = bf2_to_f2(q.x), v1 = bf2_to_f2(q.y);
            float2 v2 = bf2_to_f2(q.z), v3 = bf2_to_f2(q.w);
            acc[0] = fmaf(a, v0.x, acc[0]); acc[1] = fmaf(a, v0.y, acc[1]);
            acc[2] = fmaf(a, v1.x, acc[2]); acc[3] = fmaf(a, v1.y, acc[3]);
            acc[4] = fmaf(a, v2.x, acc[4]); acc[5] = fmaf(a, v2.y, acc[5]);
            acc[6] = fmaf(a, v3.x, acc[6]); acc[7] = fmaf(a, v3.y, acc[7]);
        }
    }
#pragma unroll
    for (int j = 0; j < 8; ++j) {
        acc[j] += __shfl_xor(acc[j], 16);
        acc[j] += __shfl_xor(acc[j], 32);
    }
    if (sub == 0) {
        float o[8];
#pragma unroll
        for (int j = 0; j < 8; ++j) o[j] = acc[j] > 0.f ? acc[j] : expm1f(acc[j]);
        uint4 wv = make_uint4(pack_bf2(o[0], o[1]), pack_bf2(o[2], o[3]),
                              pack_bf2(o[4], o[5]), pack_bf2(o[6], o[7]));
        *reinterpret_cast<uint4*>(out + (size_t)n * 128 + colbase) = wv;
    }
}

// ---------------- aggregation L3: edge-cooperative, 24 lanes/row (stride 192) ----------------
// lane: sub=lane>>5 (edge within pair), sl=lane&31; lanes sl<24 own 8 cols (16B).
__global__ __launch_bounds__(256) void gat_agg_final(const u16* __restrict__ feat,
                                                     const float* __restrict__ alpha,
                                                     const int* __restrict__ offs,
                                                     const int* __restrict__ csrc,
                                                     float* __restrict__ out) {
    __shared__ float lds[4][188];
    int wave = threadIdx.x >> 6;
    int lane = threadIdx.x & 63;
    int n = blockIdx.x * 4 + wave;
    int sub = lane >> 5, sl = lane & 31;
    bool active = sl < 24;
    int colbase = sl * 8;           // 0..184 for active lanes
    int hlo = active ? colbase / 47 : 0;
    int nb = (hlo + 1) * 47;
    int jsplit = nb - colbase;      // cols j<jsplit -> head hlo; else hlo+1 (or dead)
    bool hasHi = hlo < 3;
    int i0 = offs[n], i1 = offs[n + 1];
    float acc[8] = {0.f, 0.f, 0.f, 0.f, 0.f, 0.f, 0.f, 0.f};

    for (int i = i0; i < i1; i += 8) {
#pragma unroll
        for (int u = 0; u < 4; ++u) {
            int e = i + u * 2 + sub;
            bool valid = e < i1;
            int s = valid ? csrc[e] : 0;
            float4 av = make_float4(0.f, 0.f, 0.f, 0.f);
            if (valid) av = *reinterpret_cast<const float4*>(alpha + (size_t)e * NH);
            float wlo = selH(av, hlo);
            float whi = hasHi ? selH(av, hlo + 1) : 0.f;
            if (active) {
                uint4 q = *reinterpret_cast<const uint4*>(feat + (size_t)s * 192 + colbase);
                float2 v0 = bf2_to_f2(q.x), v1 = bf2_to_f2(q.y);
                float2 v2 = bf2_to_f2(q.z), v3 = bf2_to_f2(q.w);
                float f[8] = {v0.x, v0.y, v1.x, v1.y, v2.x, v2.y, v3.x, v3.y};
#pragma unroll
                for (int j = 0; j < 8; ++j) {
                    float wj = (j < jsplit) ? wlo : whi;
                    acc[j] = fmaf(wj, f[j], acc[j]);
                }
            }
        }
    }
#pragma unroll
    for (int j = 0; j < 8; ++j) acc[j] += __shfl_xor(acc[j], 32);
    if (sub == 0 && active) {
#pragma unroll
        for (int j = 0; j < 8; ++j) {
            int c = colbase + j;
            if (c < 188) lds[wave][c] = acc[j];
        }
    }
    __syncthreads();
    float u = (lane < 47)
                  ? 0.25f * (lds[wave][lane] + lds[wave][47 + lane] +
                             lds[wave][94 + lane] + lds[wave][141 + lane])
                  : -__builtin_inff();
    float mx = u;
#pragma unroll
    for (int o = 32; o > 0; o >>= 1) mx = fmaxf(mx, __shfl_xor(mx, o));
    float ex = (lane < 47) ? __expf(u - mx) : 0.f;
    float sm = ex;
#pragma unroll
    for (int o = 32; o > 0; o >>= 1) sm += __shfl_xor(sm, o);
    if (lane < 47) out[(size_t)n * 47 + lane] = u - mx - logf(sm);
}

// ---------------- launch ----------------

extern "C" void kernel_launch(void* const* d_in, const int* in_sizes, int n_in,
                              void* d_out, int out_size, void* d_ws, size_t ws_size,
                              hipStream_t stream) {
    const float* x = (const float*)d_in[0];
    const int* src = (const int*)d_in[1];
    const int* dst = (const int*)d_in[2];
    const float* W1 = (const float*)d_in[3];
    const float* al1 = (const float*)d_in[4];
    const float* ar1 = (const float*)d_in[5];
    const float* W2 = (const float*)d_in[6];
    const float* al2 = (const float*)d_in[7];
    const float* ar2 = (const float*)d_in[8];
    const float* W3 = (const float*)d_in[9];
    const float* al3 = (const float*)d_in[10];
    const float* ar3 = (const float*)d_in[11];
    float* out = (float*)d_out;

    char* p = (char*)d_ws;
    auto alloc = [&](size_t bytes) {
        char* r = p;
        p += (bytes + 255) & ~(size_t)255;
        return r;
    };
    u16* bufA = (u16*)alloc((size_t)N_NODES * 128 * 2);
    u16* bufC = (u16*)alloc((size_t)N_NODES * 128 * 2);
    u16* featb = (u16*)alloc((size_t)N_NODES * 192 * 2);
    float* el = (float*)alloc((size_t)N_NODES * NH * 4);
    float* er = (float*)alloc((size_t)N_NODES * NH * 4);
    float* alpha = (float*)alloc((size_t)N_EDGES * NH * 4);
    u16* wp1 = (u16*)alloc((size_t)(256 / 32) * 8 * 512 * 2);
    u16* wp2 = (u16*)alloc((size_t)(128 / 32) * 8 * 512 * 2);
    u16* wp3 = (u16*)alloc((size_t)(128 / 32) * 12 * 512 * 2);
    int* deg = (int*)alloc((size_t)N_NODES * 4);
    int* offs = (int*)alloc((size_t)(N_NODES + 1) * 4);
    int* cursor = (int*)alloc((size_t)N_NODES * 4);
    int* bsum = (int*)alloc(64 * 4);
    int* csrc = (int*)alloc((size_t)N_EDGES * 4);

    // W pre-pack
    prep_w<256, 128, 128><<<(8 * 8 * 512 + 255) / 256, 256, 0, stream>>>(W1, wp1);
    prep_w<128, 128, 128><<<(4 * 8 * 512 + 255) / 256, 256, 0, stream>>>(W2, wp2);
    prep_w<128, 188, 192><<<(4 * 12 * 512 + 255) / 256, 256, 0, stream>>>(W3, wp3);

    // CSR by dst
    hipMemsetAsync(deg, 0, (size_t)N_NODES * 4, stream);
    k_hist<<<(N_EDGES + 255) / 256, 256, 0, stream>>>(dst, deg);
    k_scan1<<<49, 1024, 0, stream>>>(deg, offs, bsum);
    k_scan2<<<1, 64, 0, stream>>>(bsum, 49);
    k_scan3<<<49, 1024, 0, stream>>>(offs, bsum, cursor);
    k_scatter<<<(N_EDGES + 255) / 256, 256, 0, stream>>>(src, dst, cursor, csrc);

    int gemm_grid = (N_NODES + 63) / 64;
    // layer 1 (dots fused)
    gemm_mfma<256, 128, 128, true, true><<<gemm_grid, 256, 0, stream>>>(x, wp1, featb, al1, ar1, el, er);
    softmax_alpha<<<N_NODES / 4, 256, 0, stream>>>(el, er, offs, csrc, alpha);
    gat_agg128<<<N_NODES / 4, 256, 0, stream>>>(featb, alpha, offs, csrc, bufA);
    // layer 2 (dots fused)
    gemm_mfma<128, 128, 128, false, true><<<gemm_grid, 256, 0, stream>>>(bufA, wp2, featb, al2, ar2, el, er);
    softmax_alpha<<<N_NODES / 4, 256, 0, stream>>>(el, er, offs, csrc, alpha);
    gat_agg128<<<N_NODES / 4, 256, 0, stream>>>(featb, alpha, offs, csrc, bufC);
    // layer 3 (dots separate: DH=47 not 16-aligned)
    gemm_mfma<128, 188, 192, false, false><<<gemm_grid, 256, 0, stream>>>(bufC, wp3, featb, nullptr, nullptr, nullptr, nullptr);
    attn_dots<47, 192><<<N_NODES / 4, 256, 0, stream>>>(featb, al3, ar3, el, er);
    softmax_alpha<<<N_NODES / 4, 256, 0, stream>>>(el, er, offs, csrc, alpha);
    gat_agg_final<<<N_NODES / 4, 256, 0, stream>>>(featb, alpha, offs, csrc, out);
}

// Round 8
// 396.612 us; speedup vs baseline: 1.0622x; 1.0622x over previous
//
#include <hip/hip_runtime.h>
#include <hip/hip_bf16.h>
#include <math.h>
#include <string.h>

#define N_NODES 50000
#define N_EDGES 800000
#define NH 4

typedef unsigned int u32;
typedef unsigned short u16;
typedef __attribute__((ext_vector_type(8))) short bf16x8;
typedef __attribute__((ext_vector_type(4))) float f32x4;

__device__ __forceinline__ u32 pack_bf2(float a, float b) {
    __hip_bfloat162 h2 = __float22bfloat162_rn(make_float2(a, b));
    u32 r;
    memcpy(&r, &h2, 4);
    return r;
}
__device__ __forceinline__ float2 bf2_to_f2(u32 u) {
    return make_float2(__uint_as_float(u << 16), __uint_as_float(u & 0xffff0000u));
}
__device__ __forceinline__ short bf16r(float f) {
    __hip_bfloat16 h = __float2bfloat16(f);
    short s;
    memcpy(&s, &h, 2);
    return s;
}
__device__ __forceinline__ float selH(float4 av, int h) {
    return h == 0 ? av.x : (h == 1 ? av.y : (h == 2 ? av.z : av.w));
}

// ---------------- CSR build ----------------

__global__ void k_hist(const int* __restrict__ dst, int* __restrict__ deg) {
    int i = blockIdx.x * 256 + threadIdx.x;
    if (i < N_EDGES) atomicAdd(&deg[dst[i]], 1);
}

__global__ __launch_bounds__(1024) void k_scan1(const int* __restrict__ deg,
                                                int* __restrict__ offs,
                                                int* __restrict__ bsum) {
    __shared__ int tmp[1024];
    int b = blockIdx.x, t = threadIdx.x;
    int i = b * 1024 + t;
    int v = (i < N_NODES) ? deg[i] : 0;
    tmp[t] = v;
    __syncthreads();
    for (int off = 1; off < 1024; off <<= 1) {
        int add = (t >= off) ? tmp[t - off] : 0;
        __syncthreads();
        tmp[t] += add;
        __syncthreads();
    }
    if (i < N_NODES) offs[i] = tmp[t] - v;
    if (t == 1023) bsum[b] = tmp[t];
}

__global__ void k_scan2(int* __restrict__ bsum, int nb) {
    if (blockIdx.x == 0 && threadIdx.x == 0) {
        int run = 0;
        for (int b = 0; b < nb; ++b) { int v = bsum[b]; bsum[b] = run; run += v; }
    }
}

__global__ __launch_bounds__(1024) void k_scan3(int* __restrict__ offs,
                                                const int* __restrict__ bsum,
                                                int* __restrict__ cursor) {
    int b = blockIdx.x, t = threadIdx.x;
    int i = b * 1024 + t;
    if (i < N_NODES) {
        int o = offs[i] + bsum[b];
        offs[i] = o;
        cursor[i] = o;
    }
    if (b == 0 && t == 0) offs[N_NODES] = N_EDGES;
}

__global__ void k_scatter(const int* __restrict__ src, const int* __restrict__ dst,
                          int* __restrict__ cursor, int* __restrict__ csrc) {
    int i = blockIdx.x * 256 + threadIdx.x;
    if (i < N_EDGES) {
        int p = atomicAdd(&cursor[dst[i]], 1);
        csrc[p] = src[i];
    }
}

// ---------------- W pre-pack into MFMA B-fragment layout ----------------
template <int K, int NOUT, int NP>
__global__ void prep_w(const float* __restrict__ W, u16* __restrict__ Wp) {
    constexpr int NT = NP / 16;
    int idx = blockIdx.x * 256 + threadIdx.x;
    int total = (K / 32) * NT * 64 * 8;
    if (idx >= total) return;
    int j = idx & 7;
    int lane = (idx >> 3) & 63;
    int rest = idx >> 9;
    int nt = rest % NT;
    int kt = rest / NT;
    int k = kt * 32 + (lane >> 4) * 8 + j;
    int col = nt * 16 + (lane & 15);
    float v = (col < NOUT) ? W[(size_t)k * NOUT + col] : 0.f;
    Wp[idx] = (u16)bf16r(v);
}

// ---------------- MFMA GEMM: feat(bf16,[N,NP]) = A @ W (+fused attn dots) ----------------
template <int K, int NOUT, int NP, bool AF32, bool DOTS>
__global__ __launch_bounds__(256) void gemm_mfma(const void* __restrict__ Av,
                                                 const u16* __restrict__ Wp,
                                                 u16* __restrict__ feat,
                                                 const float* __restrict__ al,
                                                 const float* __restrict__ ar,
                                                 float* __restrict__ el,
                                                 float* __restrict__ er) {
    constexpr int NT = NP / 16;
    constexpr int KT = K / 32;
    int w = threadIdx.x >> 6, l = threadIdx.x & 63;
    int tile_m0 = blockIdx.x * 64 + w * 16;
    int c15 = l & 15;
    int rowA = tile_m0 + c15;
    if (rowA >= N_NODES) rowA = N_NODES - 1;
    int g = l >> 4;

    f32x4 acc[NT];
#pragma unroll
    for (int nt = 0; nt < NT; ++nt) acc[nt] = (f32x4){0.f, 0.f, 0.f, 0.f};

    for (int kt = 0; kt < KT; ++kt) {
        bf16x8 a;
        if constexpr (AF32) {
            const float* ap = (const float*)Av + (size_t)rowA * K + kt * 32 + g * 8;
            float4 f0 = *reinterpret_cast<const float4*>(ap);
            float4 f1 = *reinterpret_cast<const float4*>(ap + 4);
            a[0] = bf16r(f0.x); a[1] = bf16r(f0.y); a[2] = bf16r(f0.z); a[3] = bf16r(f0.w);
            a[4] = bf16r(f1.x); a[5] = bf16r(f1.y); a[6] = bf16r(f1.z); a[7] = bf16r(f1.w);
        } else {
            a = *reinterpret_cast<const bf16x8*>((const u16*)Av + (size_t)rowA * K + kt * 32 + g * 8);
        }
        const u16* wp = Wp + ((size_t)kt * NT) * 512 + (size_t)l * 8;
#pragma unroll
        for (int nt = 0; nt < NT; ++nt) {
            bf16x8 b = *reinterpret_cast<const bf16x8*>(wp + nt * 512);
            acc[nt] = __builtin_amdgcn_mfma_f32_16x16x32_bf16(a, b, acc[nt], 0, 0, 0);
        }
    }

    int rowD0 = tile_m0 + g * 4;
#pragma unroll
    for (int nt = 0; nt < NT; ++nt) {
        int col = nt * 16 + c15;
#pragma unroll
        for (int r = 0; r < 4; ++r) {
            int row = rowD0 + r;
            if (row < N_NODES)
                feat[(size_t)row * NP + col] = (u16)bf16r(acc[nt][r]);  // pad cols: Wp=0 -> acc=0
        }
    }

    if constexpr (DOTS) {
        float alv[NT], arv[NT];
#pragma unroll
        for (int nt = 0; nt < NT; ++nt) {
            alv[nt] = al[nt * 16 + c15];
            arv[nt] = ar[nt * 16 + c15];
        }
#pragma unroll
        for (int r = 0; r < 4; ++r) {
            float hlv[NH] = {0.f, 0.f, 0.f, 0.f};
            float hrv[NH] = {0.f, 0.f, 0.f, 0.f};
#pragma unroll
            for (int nt = 0; nt < NT; ++nt) {
                constexpr int NTH = NT / NH;
                int h = nt / NTH;
                hlv[h] = fmaf(acc[nt][r], alv[nt], hlv[h]);
                hrv[h] = fmaf(acc[nt][r], arv[nt], hrv[h]);
            }
#pragma unroll
            for (int o = 1; o < 16; o <<= 1) {
#pragma unroll
                for (int j = 0; j < NH; ++j) {
                    hlv[j] += __shfl_xor(hlv[j], o);
                    hrv[j] += __shfl_xor(hrv[j], o);
                }
            }
            int row = rowD0 + r;
            if (c15 == 0 && row < N_NODES) {
                *reinterpret_cast<float4*>(el + (size_t)row * NH) =
                    make_float4(hlv[0], hlv[1], hlv[2], hlv[3]);
                *reinterpret_cast<float4*>(er + (size_t)row * NH) =
                    make_float4(hrv[0], hrv[1], hrv[2], hrv[3]);
            }
        }
    }
}

// ---------------- attention dots (layer 3 only) ----------------
template <int DH, int STRIDE>
__global__ __launch_bounds__(256) void attn_dots(const u16* __restrict__ feat,
                                                 const float* __restrict__ al,
                                                 const float* __restrict__ ar,
                                                 float* __restrict__ el,
                                                 float* __restrict__ er) {
    int wave = threadIdx.x >> 6, lane = threadIdx.x & 63;
    int n = blockIdx.x * 4 + wave;
    int h = lane >> 4, t = lane & 15;
    const u16* f = feat + (size_t)n * STRIDE + h * DH;
    const float* alh = al + h * DH;
    const float* arh = ar + h * DH;
    float sl = 0.f, sr = 0.f;
#pragma unroll
    for (int d0 = 0; d0 < DH; d0 += 16) {
        int d = d0 + t;
        if (d < DH) {
            float fv = __uint_as_float(((u32)f[d]) << 16);
            sl = fmaf(fv, alh[d], sl);
            sr = fmaf(fv, arh[d], sr);
        }
    }
#pragma unroll
    for (int o = 1; o < 16; o <<= 1) {
        sl += __shfl_xor(sl, o);
        sr += __shfl_xor(sr, o);
    }
    if (t == 0) { el[n * NH + h] = sl; er[n * NH + h] = sr; }
}

// ---------------- per-node segment softmax -> normalized alpha[E][4] ----------------
__device__ __forceinline__ float wred_max(float v) {
#pragma unroll
    for (int o = 32; o > 0; o >>= 1) v = fmaxf(v, __shfl_xor(v, o));
    return v;
}
__device__ __forceinline__ float wred_sum(float v) {
#pragma unroll
    for (int o = 32; o > 0; o >>= 1) v += __shfl_xor(v, o);
    return v;
}

__global__ __launch_bounds__(256) void softmax_alpha(const float* __restrict__ el,
                                                     const float* __restrict__ er,
                                                     const int* __restrict__ offs,
                                                     const int* __restrict__ csrc,
                                                     float* __restrict__ alpha) {
    const float NEG = -__builtin_inff();
    int wave = threadIdx.x >> 6, lane = threadIdx.x & 63;
    int n = blockIdx.x * 4 + wave;
    int i0 = offs[n], i1 = offs[n + 1];
    if (i0 >= i1) return;
    float4 erv = *reinterpret_cast<const float4*>(er + (size_t)n * NH);

    if (i1 - i0 <= 64) {
        int i = i0 + lane;
        bool act = i < i1;
        int src = act ? csrc[i] : 0;
        float4 elv = make_float4(0.f, 0.f, 0.f, 0.f);
        if (act) elv = *reinterpret_cast<const float4*>(el + (size_t)src * NH);
        float e0 = elv.x + erv.x; e0 = e0 >= 0.f ? e0 : 0.2f * e0;
        float e1 = elv.y + erv.y; e1 = e1 >= 0.f ? e1 : 0.2f * e1;
        float e2 = elv.z + erv.z; e2 = e2 >= 0.f ? e2 : 0.2f * e2;
        float e3 = elv.w + erv.w; e3 = e3 >= 0.f ? e3 : 0.2f * e3;
        if (!act) { e0 = NEG; e1 = NEG; e2 = NEG; e3 = NEG; }
        float m0 = wred_max(e0), m1 = wred_max(e1), m2 = wred_max(e2), m3 = wred_max(e3);
        float p0 = act ? __expf(e0 - m0) : 0.f;
        float p1 = act ? __expf(e1 - m1) : 0.f;
        float p2 = act ? __expf(e2 - m2) : 0.f;
        float p3 = act ? __expf(e3 - m3) : 0.f;
        float s0 = wred_sum(p0), s1 = wred_sum(p1), s2 = wred_sum(p2), s3 = wred_sum(p3);
        if (act) {
            float4 a = make_float4(p0 / s0, p1 / s1, p2 / s2, p3 / s3);
            *reinterpret_cast<float4*>(alpha + (size_t)i * NH) = a;
        }
        return;
    }

    float m0 = NEG, m1 = NEG, m2 = NEG, m3 = NEG;
    float s0 = 0.f, s1 = 0.f, s2 = 0.f, s3 = 0.f;
    for (int base = i0; base < i1; base += 64) {
        int i = base + lane;
        bool act = i < i1;
        int src = act ? csrc[i] : 0;
        float4 elv = make_float4(0.f, 0.f, 0.f, 0.f);
        if (act) elv = *reinterpret_cast<const float4*>(el + (size_t)src * NH);
        float e0 = elv.x + erv.x; e0 = e0 >= 0.f ? e0 : 0.2f * e0;
        float e1 = elv.y + erv.y; e1 = e1 >= 0.f ? e1 : 0.2f * e1;
        float e2 = elv.z + erv.z; e2 = e2 >= 0.f ? e2 : 0.2f * e2;
        float e3 = elv.w + erv.w; e3 = e3 >= 0.f ? e3 : 0.2f * e3;
        if (!act) { e0 = NEG; e1 = NEG; e2 = NEG; e3 = NEG; }
        float c0 = wred_max(e0), c1 = wred_max(e1), c2 = wred_max(e2), c3 = wred_max(e3);
        float nm0 = fmaxf(m0, c0), nm1 = fmaxf(m1, c1), nm2 = fmaxf(m2, c2), nm3 = fmaxf(m3, c3);
        float p0 = act ? __expf(e0 - nm0) : 0.f;
        float p1 = act ? __expf(e1 - nm1) : 0.f;
        float p2 = act ? __expf(e2 - nm2) : 0.f;
        float p3 = act ? __expf(e3 - nm3) : 0.f;
        float S0 = wred_sum(p0), S1 = wred_sum(p1), S2 = wred_sum(p2), S3 = wred_sum(p3);
        s0 = s0 * __expf(m0 - nm0) + S0; m0 = nm0;
        s1 = s1 * __expf(m1 - nm1) + S1; m1 = nm1;
        s2 = s2 * __expf(m2 - nm2) + S2; m2 = nm2;
        s3 = s3 * __expf(m3 - nm3) + S3; m3 = nm3;
    }
    float v0 = 1.f / s0, v1 = 1.f / s1, v2 = 1.f / s2, v3 = 1.f / s3;
    for (int base = i0; base < i1; base += 64) {
        int i = base + lane;
        bool act = i < i1;
        int src = act ? csrc[i] : 0;
        float4 elv = make_float4(0.f, 0.f, 0.f, 0.f);
        if (act) elv = *reinterpret_cast<const float4*>(el + (size_t)src * NH);
        float e0 = elv.x + erv.x; e0 = e0 >= 0.f ? e0 : 0.2f * e0;
        float e1 = elv.y + erv.y; e1 = e1 >= 0.f ? e1 : 0.2f * e1;
        float e2 = elv.z + erv.z; e2 = e2 >= 0.f ? e2 : 0.2f * e2;
        float e3 = elv.w + erv.w; e3 = e3 >= 0.f ? e3 : 0.2f * e3;
        if (act) {
            float4 a = make_float4(__expf(e0 - m0) * v0, __expf(e1 - m1) * v1,
                                   __expf(e2 - m2) * v2, __expf(e3 - m3) * v3);
            *reinterpret_cast<float4*>(alpha + (size_t)i * NH) = a;
        }
    }
}

// ---------------- aggregation L1-2 (128 cols): 8-deep load pipeline ----------------
__global__ __launch_bounds__(256) void gat_agg128(const u16* __restrict__ feat,
                                                  const float* __restrict__ alpha,
                                                  const int* __restrict__ offs,
                                                  const int* __restrict__ csrc,
                                                  u16* __restrict__ out) {
    int wave = threadIdx.x >> 6;
    int lane = threadIdx.x & 63;
    int n = blockIdx.x * 4 + wave;
    int h = lane >> 4;
    int i0 = offs[n], i1 = offs[n + 1];
    float ax = 0.f, ay = 0.f;
    int i = i0;
    for (; i + 8 <= i1; i += 8) {
        int s[8];
        float a[8];
        u32 u[8];
#pragma unroll
        for (int j = 0; j < 8; ++j) s[j] = csrc[i + j];
#pragma unroll
        for (int j = 0; j < 8; ++j) a[j] = alpha[(size_t)(i + j) * NH + h];
#pragma unroll
        for (int j = 0; j < 8; ++j)
            u[j] = *reinterpret_cast<const u32*>(feat + (size_t)s[j] * 128 + 2 * lane);
#pragma unroll
        for (int j = 0; j < 8; ++j) {
            float2 v = bf2_to_f2(u[j]);
            ax = fmaf(a[j], v.x, ax);
            ay = fmaf(a[j], v.y, ay);
        }
    }
    for (; i < i1; ++i) {
        int s = csrc[i];
        float a = alpha[(size_t)i * NH + h];
        u32 u = *reinterpret_cast<const u32*>(feat + (size_t)s * 128 + 2 * lane);
        float2 v = bf2_to_f2(u);
        ax = fmaf(a, v.x, ax); ay = fmaf(a, v.y, ay);
    }
    float ox = ax > 0.f ? ax : expm1f(ax);
    float oy = ay > 0.f ? ay : expm1f(ay);
    *reinterpret_cast<u32*>(out + (size_t)n * 128 + 2 * lane) = pack_bf2(ox, oy);
}

// ---------------- aggregation L3 (188 cols, stride 192): 8-deep + mean + log_softmax ----
__global__ __launch_bounds__(256) void gat_agg_final(const u16* __restrict__ feat,
                                                     const float* __restrict__ alpha,
                                                     const int* __restrict__ offs,
                                                     const int* __restrict__ csrc,
                                                     float* __restrict__ out) {
    __shared__ float lds[4][188];
    int wave = threadIdx.x >> 6;
    int lane = threadIdx.x & 63;
    int n = blockIdx.x * 4 + wave;
    int e0 = 2 * lane;
    int h00 = e0 / 47;
    int h01 = (e0 + 1) / 47;
    bool act30 = lane < 30;
    int h10 = act30 ? (128 + e0) / 47 : 2;
    int h11 = act30 ? (129 + e0) / 47 : 2;
    int i0 = offs[n], i1 = offs[n + 1];
    float a00 = 0.f, a01 = 0.f, a10 = 0.f, a11 = 0.f;

    auto selLo = [](float4 av, int h) { return h == 0 ? av.x : (h == 1 ? av.y : av.z); };
    auto selHi = [](float4 av, int h) { return h == 2 ? av.z : av.w; };

    int i = i0;
    for (; i + 8 <= i1; i += 8) {
        int s[8];
        float4 av[8];
        u32 u0[8], u1[8];
#pragma unroll
        for (int j = 0; j < 8; ++j) s[j] = csrc[i + j];
#pragma unroll
        for (int j = 0; j < 8; ++j)
            av[j] = *reinterpret_cast<const float4*>(alpha + (size_t)(i + j) * NH);
#pragma unroll
        for (int j = 0; j < 8; ++j) {
            const u16* r = feat + (size_t)s[j] * 192;
            u0[j] = *reinterpret_cast<const u32*>(r + e0);
            u1[j] = act30 ? *reinterpret_cast<const u32*>(r + 128 + e0) : 0u;
        }
#pragma unroll
        for (int j = 0; j < 8; ++j) {
            float2 v0 = bf2_to_f2(u0[j]);
            float2 v1 = bf2_to_f2(u1[j]);
            a00 = fmaf(selLo(av[j], h00), v0.x, a00);
            a01 = fmaf(selLo(av[j], h01), v0.y, a01);
            a10 = fmaf(selHi(av[j], h10), v1.x, a10);
            a11 = fmaf(selHi(av[j], h11), v1.y, a11);
        }
    }
    for (; i < i1; ++i) {
        int s = csrc[i];
        float4 av = *reinterpret_cast<const float4*>(alpha + (size_t)i * NH);
        const u16* r = feat + (size_t)s * 192;
        u32 u0 = *reinterpret_cast<const u32*>(r + e0);
        u32 u1 = act30 ? *reinterpret_cast<const u32*>(r + 128 + e0) : 0u;
        float2 v0 = bf2_to_f2(u0);
        float2 v1 = bf2_to_f2(u1);
        a00 = fmaf(selLo(av, h00), v0.x, a00);
        a01 = fmaf(selLo(av, h01), v0.y, a01);
        a10 = fmaf(selHi(av, h10), v1.x, a10);
        a11 = fmaf(selHi(av, h11), v1.y, a11);
    }
    lds[wave][e0] = a00;
    lds[wave][e0 + 1] = a01;
    if (act30) {
        lds[wave][128 + e0] = a10;
        lds[wave][129 + e0] = a11;
    }
    __syncthreads();
    float u = (lane < 47)
                  ? 0.25f * (lds[wave][lane] + lds[wave][47 + lane] +
                             lds[wave][94 + lane] + lds[wave][141 + lane])
                  : -__builtin_inff();
    float mx = u;
#pragma unroll
    for (int o = 32; o > 0; o >>= 1) mx = fmaxf(mx, __shfl_xor(mx, o));
    float ex = (lane < 47) ? __expf(u - mx) : 0.f;
    float sm = ex;
#pragma unroll
    for (int o = 32; o > 0; o >>= 1) sm += __shfl_xor(sm, o);
    if (lane < 47) out[(size_t)n * 47 + lane] = u - mx - logf(sm);
}

// ---------------- launch ----------------

extern "C" void kernel_launch(void* const* d_in, const int* in_sizes, int n_in,
                              void* d_out, int out_size, void* d_ws, size_t ws_size,
                              hipStream_t stream) {
    const float* x = (const float*)d_in[0];
    const int* src = (const int*)d_in[1];
    const int* dst = (const int*)d_in[2];
    const float* W1 = (const float*)d_in[3];
    const float* al1 = (const float*)d_in[4];
    const float* ar1 = (const float*)d_in[5];
    const float* W2 = (const float*)d_in[6];
    const float* al2 = (const float*)d_in[7];
    const float* ar2 = (const float*)d_in[8];
    const float* W3 = (const float*)d_in[9];
    const float* al3 = (const float*)d_in[10];
    const float* ar3 = (const float*)d_in[11];
    float* out = (float*)d_out;

    char* p = (char*)d_ws;
    auto alloc = [&](size_t bytes) {
        char* r = p;
        p += (bytes + 255) & ~(size_t)255;
        return r;
    };
    u16* bufA = (u16*)alloc((size_t)N_NODES * 128 * 2);
    u16* bufC = (u16*)alloc((size_t)N_NODES * 128 * 2);
    u16* featb = (u16*)alloc((size_t)N_NODES * 192 * 2);
    float* el = (float*)alloc((size_t)N_NODES * NH * 4);
    float* er = (float*)alloc((size_t)N_NODES * NH * 4);
    float* alpha = (float*)alloc((size_t)N_EDGES * NH * 4);
    u16* wp1 = (u16*)alloc((size_t)(256 / 32) * 8 * 512 * 2);
    u16* wp2 = (u16*)alloc((size_t)(128 / 32) * 8 * 512 * 2);
    u16* wp3 = (u16*)alloc((size_t)(128 / 32) * 12 * 512 * 2);
    int* deg = (int*)alloc((size_t)N_NODES * 4);
    int* offs = (int*)alloc((size_t)(N_NODES + 1) * 4);
    int* cursor = (int*)alloc((size_t)N_NODES * 4);
    int* bsum = (int*)alloc(64 * 4);
    int* csrc = (int*)alloc((size_t)N_EDGES * 4);

    // W pre-pack
    prep_w<256, 128, 128><<<(8 * 8 * 512 + 255) / 256, 256, 0, stream>>>(W1, wp1);
    prep_w<128, 128, 128><<<(4 * 8 * 512 + 255) / 256, 256, 0, stream>>>(W2, wp2);
    prep_w<128, 188, 192><<<(4 * 12 * 512 + 255) / 256, 256, 0, stream>>>(W3, wp3);

    // CSR by dst
    hipMemsetAsync(deg, 0, (size_t)N_NODES * 4, stream);
    k_hist<<<(N_EDGES + 255) / 256, 256, 0, stream>>>(dst, deg);
    k_scan1<<<49, 1024, 0, stream>>>(deg, offs, bsum);
    k_scan2<<<1, 64, 0, stream>>>(bsum, 49);
    k_scan3<<<49, 1024, 0, stream>>>(offs, bsum, cursor);
    k_scatter<<<(N_EDGES + 255) / 256, 256, 0, stream>>>(src, dst, cursor, csrc);

    int gemm_grid = (N_NODES + 63) / 64;
    // layer 1 (dots fused)
    gemm_mfma<256, 128, 128, true, true><<<gemm_grid, 256, 0, stream>>>(x, wp1, featb, al1, ar1, el, er);
    softmax_alpha<<<N_NODES / 4, 256, 0, stream>>>(el, er, offs, csrc, alpha);
    gat_agg128<<<N_NODES / 4, 256, 0, stream>>>(featb, alpha, offs, csrc, bufA);
    // layer 2 (dots fused)
    gemm_mfma<128, 128, 128, false, true><<<gemm_grid, 256, 0, stream>>>(bufA, wp2, featb, al2, ar2, el, er);
    softmax_alpha<<<N_NODES / 4, 256, 0, stream>>>(el, er, offs, csrc, alpha);
    gat_agg128<<<N_NODES / 4, 256, 0, stream>>>(featb, alpha, offs, csrc, bufC);
    // layer 3 (dots separate: DH=47 not 16-aligned)
    gemm_mfma<128, 188, 192, false, false><<<gemm_grid, 256, 0, stream>>>(bufC, wp3, featb, nullptr, nullptr, nullptr, nullptr);
    attn_dots<47, 192><<<N_NODES / 4, 256, 0, stream>>>(featb, al3, ar3, el, er);
    softmax_alpha<<<N_NODES / 4, 256, 0, stream>>>(el, er, offs, csrc, alpha);
    gat_agg_final<<<N_NODES / 4, 256, 0, stream>>>(featb, alpha, offs, csrc, out);
}

// Round 9
// 336.047 us; speedup vs baseline: 1.2536x; 1.1802x over previous
//
#include <hip/hip_runtime.h>
#include <hip/hip_bf16.h>
#include <math.h>
#include <string.h>

#define N_NODES 50000
#define N_EDGES 800000
#define NH 4

typedef unsigned int u32;
typedef unsigned short u16;
typedef __attribute__((ext_vector_type(8))) short bf16x8;
typedef __attribute__((ext_vector_type(4))) float f32x4;

__device__ __forceinline__ u32 pack_bf2(float a, float b) {
    __hip_bfloat162 h2 = __float22bfloat162_rn(make_float2(a, b));
    u32 r;
    memcpy(&r, &h2, 4);
    return r;
}
__device__ __forceinline__ float2 bf2_to_f2(u32 u) {
    return make_float2(__uint_as_float(u << 16), __uint_as_float(u & 0xffff0000u));
}
__device__ __forceinline__ short bf16r(float f) {
    __hip_bfloat16 h = __float2bfloat16(f);
    short s;
    memcpy(&s, &h, 2);
    return s;
}

__device__ __forceinline__ float wred_max(float v) {
#pragma unroll
    for (int o = 32; o > 0; o >>= 1) v = fmaxf(v, __shfl_xor(v, o));
    return v;
}
__device__ __forceinline__ float wred_sum(float v) {
#pragma unroll
    for (int o = 32; o > 0; o >>= 1) v += __shfl_xor(v, o);
    return v;
}

// ---------------- CSR build ----------------

__global__ void k_hist(const int* __restrict__ dst, int* __restrict__ deg) {
    int i = blockIdx.x * 256 + threadIdx.x;
    if (i < N_EDGES) atomicAdd(&deg[dst[i]], 1);
}

__global__ __launch_bounds__(1024) void k_scan1(const int* __restrict__ deg,
                                                int* __restrict__ offs,
                                                int* __restrict__ bsum) {
    __shared__ int tmp[1024];
    int b = blockIdx.x, t = threadIdx.x;
    int i = b * 1024 + t;
    int v = (i < N_NODES) ? deg[i] : 0;
    tmp[t] = v;
    __syncthreads();
    for (int off = 1; off < 1024; off <<= 1) {
        int add = (t >= off) ? tmp[t - off] : 0;
        __syncthreads();
        tmp[t] += add;
        __syncthreads();
    }
    if (i < N_NODES) offs[i] = tmp[t] - v;
    if (t == 1023) bsum[b] = tmp[t];
}

__global__ void k_scan2(int* __restrict__ bsum, int nb) {
    if (blockIdx.x == 0 && threadIdx.x == 0) {
        int run = 0;
        for (int b = 0; b < nb; ++b) { int v = bsum[b]; bsum[b] = run; run += v; }
    }
}

__global__ __launch_bounds__(1024) void k_scan3(int* __restrict__ offs,
                                                const int* __restrict__ bsum,
                                                int* __restrict__ cursor) {
    int b = blockIdx.x, t = threadIdx.x;
    int i = b * 1024 + t;
    if (i < N_NODES) {
        int o = offs[i] + bsum[b];
        offs[i] = o;
        cursor[i] = o;
    }
    if (b == 0 && t == 0) offs[N_NODES] = N_EDGES;
}

__global__ void k_scatter(const int* __restrict__ src, const int* __restrict__ dst,
                          int* __restrict__ cursor, int* __restrict__ csrc) {
    int i = blockIdx.x * 256 + threadIdx.x;
    if (i < N_EDGES) {
        int p = atomicAdd(&cursor[dst[i]], 1);
        csrc[p] = src[i];
    }
}

// ---------------- W pre-pack into MFMA B-fragment layout ----------------
template <int K, int NOUT, int NP>
__global__ void prep_w(const float* __restrict__ W, u16* __restrict__ Wp) {
    constexpr int NT = NP / 16;
    int idx = blockIdx.x * 256 + threadIdx.x;
    int total = (K / 32) * NT * 64 * 8;
    if (idx >= total) return;
    int j = idx & 7;
    int lane = (idx >> 3) & 63;
    int rest = idx >> 9;
    int nt = rest % NT;
    int kt = rest / NT;
    int k = kt * 32 + (lane >> 4) * 8 + j;
    int col = nt * 16 + (lane & 15);
    float v = (col < NOUT) ? W[(size_t)k * NOUT + col] : 0.f;
    Wp[idx] = (u16)bf16r(v);
}

// ---------------- MFMA GEMM: feat(bf16,[N,NP]) = A @ W (+fused attn dots) ----------------
template <int K, int NOUT, int NP, bool AF32, bool DOTS>
__global__ __launch_bounds__(256) void gemm_mfma(const void* __restrict__ Av,
                                                 const u16* __restrict__ Wp,
                                                 u16* __restrict__ feat,
                                                 const float* __restrict__ al,
                                                 const float* __restrict__ ar,
                                                 float* __restrict__ el,
                                                 float* __restrict__ er) {
    constexpr int NT = NP / 16;
    constexpr int KT = K / 32;
    int w = threadIdx.x >> 6, l = threadIdx.x & 63;
    int tile_m0 = blockIdx.x * 64 + w * 16;
    int c15 = l & 15;
    int rowA = tile_m0 + c15;
    if (rowA >= N_NODES) rowA = N_NODES - 1;
    int g = l >> 4;

    f32x4 acc[NT];
#pragma unroll
    for (int nt = 0; nt < NT; ++nt) acc[nt] = (f32x4){0.f, 0.f, 0.f, 0.f};

    for (int kt = 0; kt < KT; ++kt) {
        bf16x8 a;
        if constexpr (AF32) {
            const float* ap = (const float*)Av + (size_t)rowA * K + kt * 32 + g * 8;
            float4 f0 = *reinterpret_cast<const float4*>(ap);
            float4 f1 = *reinterpret_cast<const float4*>(ap + 4);
            a[0] = bf16r(f0.x); a[1] = bf16r(f0.y); a[2] = bf16r(f0.z); a[3] = bf16r(f0.w);
            a[4] = bf16r(f1.x); a[5] = bf16r(f1.y); a[6] = bf16r(f1.z); a[7] = bf16r(f1.w);
        } else {
            a = *reinterpret_cast<const bf16x8*>((const u16*)Av + (size_t)rowA * K + kt * 32 + g * 8);
        }
        const u16* wp = Wp + ((size_t)kt * NT) * 512 + (size_t)l * 8;
#pragma unroll
        for (int nt = 0; nt < NT; ++nt) {
            bf16x8 b = *reinterpret_cast<const bf16x8*>(wp + nt * 512);
            acc[nt] = __builtin_amdgcn_mfma_f32_16x16x32_bf16(a, b, acc[nt], 0, 0, 0);
        }
    }

    int rowD0 = tile_m0 + g * 4;
#pragma unroll
    for (int nt = 0; nt < NT; ++nt) {
        int col = nt * 16 + c15;
#pragma unroll
        for (int r = 0; r < 4; ++r) {
            int row = rowD0 + r;
            if (row < N_NODES)
                feat[(size_t)row * NP + col] = (u16)bf16r(acc[nt][r]);
        }
    }

    if constexpr (DOTS) {
        float alv[NT], arv[NT];
#pragma unroll
        for (int nt = 0; nt < NT; ++nt) {
            alv[nt] = al[nt * 16 + c15];
            arv[nt] = ar[nt * 16 + c15];
        }
#pragma unroll
        for (int r = 0; r < 4; ++r) {
            float hlv[NH] = {0.f, 0.f, 0.f, 0.f};
            float hrv[NH] = {0.f, 0.f, 0.f, 0.f};
#pragma unroll
            for (int nt = 0; nt < NT; ++nt) {
                constexpr int NTH = NT / NH;
                int h = nt / NTH;
                hlv[h] = fmaf(acc[nt][r], alv[nt], hlv[h]);
                hrv[h] = fmaf(acc[nt][r], arv[nt], hrv[h]);
            }
#pragma unroll
            for (int o = 1; o < 16; o <<= 1) {
#pragma unroll
                for (int j = 0; j < NH; ++j) {
                    hlv[j] += __shfl_xor(hlv[j], o);
                    hrv[j] += __shfl_xor(hrv[j], o);
                }
            }
            int row = rowD0 + r;
            if (c15 == 0 && row < N_NODES) {
                *reinterpret_cast<float4*>(el + (size_t)row * NH) =
                    make_float4(hlv[0], hlv[1], hlv[2], hlv[3]);
                *reinterpret_cast<float4*>(er + (size_t)row * NH) =
                    make_float4(hrv[0], hrv[1], hrv[2], hrv[3]);
            }
        }
    }
}

// ---------------- attention dots (layer 3 only) ----------------
template <int DH, int STRIDE>
__global__ __launch_bounds__(256) void attn_dots(const u16* __restrict__ feat,
                                                 const float* __restrict__ al,
                                                 const float* __restrict__ ar,
                                                 float* __restrict__ el,
                                                 float* __restrict__ er) {
    int wave = threadIdx.x >> 6, lane = threadIdx.x & 63;
    int n = blockIdx.x * 4 + wave;
    int h = lane >> 4, t = lane & 15;
    const u16* f = feat + (size_t)n * STRIDE + h * DH;
    const float* alh = al + h * DH;
    const float* arh = ar + h * DH;
    float sl = 0.f, sr = 0.f;
#pragma unroll
    for (int d0 = 0; d0 < DH; d0 += 16) {
        int d = d0 + t;
        if (d < DH) {
            float fv = __uint_as_float(((u32)f[d]) << 16);
            sl = fmaf(fv, alh[d], sl);
            sr = fmaf(fv, arh[d], sr);
        }
    }
#pragma unroll
    for (int o = 1; o < 16; o <<= 1) {
        sl += __shfl_xor(sl, o);
        sr += __shfl_xor(sr, o);
    }
    if (t == 0) { el[n * NH + h] = sl; er[n * NH + h] = sr; }
}

// ---------------- helper: per-chunk alpha into LDS (one wave, <=64 edges) ----------------
// returns srcn for this lane's edge (0 if inactive). alpha written to lal[wave][lane][0..3].
__device__ __forceinline__ int alpha_chunk(const float* __restrict__ el,
                                           const int* __restrict__ csrc,
                                           float4 erv, int base, int i1, int wave,
                                           float4 mref, float4 vinv, bool online,
                                           float (*lal)[64][4], int lane) {
    int e = base + lane;
    bool act = e < i1;
    int srcn = act ? csrc[e] : 0;
    float4 elv = make_float4(0.f, 0.f, 0.f, 0.f);
    if (act) elv = *reinterpret_cast<const float4*>(el + (size_t)srcn * NH);
    float e0 = elv.x + erv.x; e0 = e0 >= 0.f ? e0 : 0.2f * e0;
    float e1 = elv.y + erv.y; e1 = e1 >= 0.f ? e1 : 0.2f * e1;
    float e2 = elv.z + erv.z; e2 = e2 >= 0.f ? e2 : 0.2f * e2;
    float e3 = elv.w + erv.w; e3 = e3 >= 0.f ? e3 : 0.2f * e3;
    float4 a4;
    if (online) {
        // one-chunk node: compute max & sum in-wave
        const float NEG = -__builtin_inff();
        float f0 = act ? e0 : NEG, f1 = act ? e1 : NEG, f2 = act ? e2 : NEG, f3 = act ? e3 : NEG;
        float m0 = wred_max(f0), m1 = wred_max(f1), m2 = wred_max(f2), m3 = wred_max(f3);
        float p0 = act ? __expf(e0 - m0) : 0.f;
        float p1 = act ? __expf(e1 - m1) : 0.f;
        float p2 = act ? __expf(e2 - m2) : 0.f;
        float p3 = act ? __expf(e3 - m3) : 0.f;
        float s0 = wred_sum(p0), s1 = wred_sum(p1), s2 = wred_sum(p2), s3 = wred_sum(p3);
        a4 = make_float4(act ? p0 / s0 : 0.f, act ? p1 / s1 : 0.f,
                         act ? p2 / s2 : 0.f, act ? p3 / s3 : 0.f);
    } else {
        a4 = make_float4(act ? __expf(e0 - mref.x) * vinv.x : 0.f,
                         act ? __expf(e1 - mref.y) * vinv.y : 0.f,
                         act ? __expf(e2 - mref.z) * vinv.z : 0.f,
                         act ? __expf(e3 - mref.w) * vinv.w : 0.f);
    }
    *reinterpret_cast<float4*>(&lal[wave][lane][0]) = a4;
    return srcn;
}

// global-stats pass for deg>64 nodes
__device__ __forceinline__ void stats_pass(const float* __restrict__ el,
                                           const int* __restrict__ csrc,
                                           float4 erv, int i0, int i1, int lane,
                                           float4& mout, float4& vout) {
    const float NEG = -__builtin_inff();
    float m0 = NEG, m1 = NEG, m2 = NEG, m3 = NEG;
    float s0 = 0.f, s1 = 0.f, s2 = 0.f, s3 = 0.f;
    for (int base = i0; base < i1; base += 64) {
        int i = base + lane;
        bool act = i < i1;
        int srcn = act ? csrc[i] : 0;
        float4 elv = make_float4(0.f, 0.f, 0.f, 0.f);
        if (act) elv = *reinterpret_cast<const float4*>(el + (size_t)srcn * NH);
        float e0 = elv.x + erv.x; e0 = e0 >= 0.f ? e0 : 0.2f * e0;
        float e1 = elv.y + erv.y; e1 = e1 >= 0.f ? e1 : 0.2f * e1;
        float e2 = elv.z + erv.z; e2 = e2 >= 0.f ? e2 : 0.2f * e2;
        float e3 = elv.w + erv.w; e3 = e3 >= 0.f ? e3 : 0.2f * e3;
        if (!act) { e0 = NEG; e1 = NEG; e2 = NEG; e3 = NEG; }
        float c0 = wred_max(e0), c1 = wred_max(e1), c2 = wred_max(e2), c3 = wred_max(e3);
        float nm0 = fmaxf(m0, c0), nm1 = fmaxf(m1, c1), nm2 = fmaxf(m2, c2), nm3 = fmaxf(m3, c3);
        float p0 = act ? __expf(e0 - nm0) : 0.f;
        float p1 = act ? __expf(e1 - nm1) : 0.f;
        float p2 = act ? __expf(e2 - nm2) : 0.f;
        float p3 = act ? __expf(e3 - nm3) : 0.f;
        float S0 = wred_sum(p0), S1 = wred_sum(p1), S2 = wred_sum(p2), S3 = wred_sum(p3);
        s0 = s0 * __expf(m0 - nm0) + S0; m0 = nm0;
        s1 = s1 * __expf(m1 - nm1) + S1; m1 = nm1;
        s2 = s2 * __expf(m2 - nm2) + S2; m2 = nm2;
        s3 = s3 * __expf(m3 - nm3) + S3; m3 = nm3;
    }
    mout = make_float4(m0, m1, m2, m3);
    vout = make_float4(1.f / s0, 1.f / s1, 1.f / s2, 1.f / s3);
}

// ---------------- fused softmax+aggregation, layers 1-2 (128 cols) ----------------
__global__ __launch_bounds__(256) void gat_agg128(const u16* __restrict__ feat,
                                                  const float* __restrict__ el,
                                                  const float* __restrict__ er,
                                                  const int* __restrict__ offs,
                                                  const int* __restrict__ csrc,
                                                  u16* __restrict__ out) {
    __shared__ float lal[4][64][4];
    int wave = threadIdx.x >> 6;
    int lane = threadIdx.x & 63;
    int n = blockIdx.x * 4 + wave;
    int h = lane >> 4;
    int i0 = offs[n], i1 = offs[n + 1];
    int d = i1 - i0;
    float ax = 0.f, ay = 0.f;
    if (d > 0) {
        float4 erv = *reinterpret_cast<const float4*>(er + (size_t)n * NH);
        float4 mref = make_float4(0.f, 0.f, 0.f, 0.f), vinv = mref;
        bool onechunk = d <= 64;
        if (!onechunk) stats_pass(el, csrc, erv, i0, i1, lane, mref, vinv);
        for (int base = i0; base < i1; base += 64) {
            int srcn = alpha_chunk(el, csrc, erv, base, i1, wave, mref, vinv, onechunk, lal, lane);
            int cnt = i1 - base; if (cnt > 64) cnt = 64;
            int cpad = (cnt + 3) & ~3;
            for (int j = 0; j < cpad; j += 4) {
                int s0 = __shfl(srcn, j + 0);
                int s1 = __shfl(srcn, j + 1);
                int s2 = __shfl(srcn, j + 2);
                int s3 = __shfl(srcn, j + 3);
                float a0 = lal[wave][j + 0][h];
                float a1 = lal[wave][j + 1][h];
                float a2 = lal[wave][j + 2][h];
                float a3 = lal[wave][j + 3][h];
                u32 q0 = *reinterpret_cast<const u32*>(feat + (size_t)s0 * 128 + 2 * lane);
                u32 q1 = *reinterpret_cast<const u32*>(feat + (size_t)s1 * 128 + 2 * lane);
                u32 q2 = *reinterpret_cast<const u32*>(feat + (size_t)s2 * 128 + 2 * lane);
                u32 q3 = *reinterpret_cast<const u32*>(feat + (size_t)s3 * 128 + 2 * lane);
                float2 v;
                v = bf2_to_f2(q0); ax = fmaf(a0, v.x, ax); ay = fmaf(a0, v.y, ay);
                v = bf2_to_f2(q1); ax = fmaf(a1, v.x, ax); ay = fmaf(a1, v.y, ay);
                v = bf2_to_f2(q2); ax = fmaf(a2, v.x, ax); ay = fmaf(a2, v.y, ay);
                v = bf2_to_f2(q3); ax = fmaf(a3, v.x, ax); ay = fmaf(a3, v.y, ay);
            }
        }
    }
    float ox = ax > 0.f ? ax : expm1f(ax);
    float oy = ay > 0.f ? ay : expm1f(ay);
    *reinterpret_cast<u32*>(out + (size_t)n * 128 + 2 * lane) = pack_bf2(ox, oy);
}

// ---------------- fused softmax+aggregation, layer 3 (188 cols, stride 192) ----------------
__global__ __launch_bounds__(256) void gat_agg_final(const u16* __restrict__ feat,
                                                     const float* __restrict__ el,
                                                     const float* __restrict__ er,
                                                     const int* __restrict__ offs,
                                                     const int* __restrict__ csrc,
                                                     float* __restrict__ out) {
    __shared__ float lal[4][64][4];
    __shared__ float lds[4][188];
    int wave = threadIdx.x >> 6;
    int lane = threadIdx.x & 63;
    int n = blockIdx.x * 4 + wave;
    int e0 = 2 * lane;
    int h00 = e0 / 47;
    int h01 = (e0 + 1) / 47;
    bool act30 = lane < 30;
    int h10 = act30 ? (128 + e0) / 47 : 2;
    int h11 = act30 ? (129 + e0) / 47 : 2;
    int i0 = offs[n], i1 = offs[n + 1];
    int d = i1 - i0;
    float a00 = 0.f, a01 = 0.f, a10 = 0.f, a11 = 0.f;
    if (d > 0) {
        float4 erv = *reinterpret_cast<const float4*>(er + (size_t)n * NH);
        float4 mref = make_float4(0.f, 0.f, 0.f, 0.f), vinv = mref;
        bool onechunk = d <= 64;
        if (!onechunk) stats_pass(el, csrc, erv, i0, i1, lane, mref, vinv);
        for (int base = i0; base < i1; base += 64) {
            int srcn = alpha_chunk(el, csrc, erv, base, i1, wave, mref, vinv, onechunk, lal, lane);
            int cnt = i1 - base; if (cnt > 64) cnt = 64;
            int cpad = (cnt + 1) & ~1;
            for (int j = 0; j < cpad; j += 2) {
                int sA = __shfl(srcn, j + 0);
                int sB = __shfl(srcn, j + 1);
                float wA00 = lal[wave][j + 0][h00], wA01 = lal[wave][j + 0][h01];
                float wA10 = lal[wave][j + 0][h10], wA11 = lal[wave][j + 0][h11];
                float wB00 = lal[wave][j + 1][h00], wB01 = lal[wave][j + 1][h01];
                float wB10 = lal[wave][j + 1][h10], wB11 = lal[wave][j + 1][h11];
                const u16* rA = feat + (size_t)sA * 192;
                const u16* rB = feat + (size_t)sB * 192;
                u32 uA0 = *reinterpret_cast<const u32*>(rA + e0);
                u32 uB0 = *reinterpret_cast<const u32*>(rB + e0);
                u32 uA1 = act30 ? *reinterpret_cast<const u32*>(rA + 128 + e0) : 0u;
                u32 uB1 = act30 ? *reinterpret_cast<const u32*>(rB + 128 + e0) : 0u;
                float2 v;
                v = bf2_to_f2(uA0); a00 = fmaf(wA00, v.x, a00); a01 = fmaf(wA01, v.y, a01);
                v = bf2_to_f2(uA1); a10 = fmaf(wA10, v.x, a10); a11 = fmaf(wA11, v.y, a11);
                v = bf2_to_f2(uB0); a00 = fmaf(wB00, v.x, a00); a01 = fmaf(wB01, v.y, a01);
                v = bf2_to_f2(uB1); a10 = fmaf(wB10, v.x, a10); a11 = fmaf(wB11, v.y, a11);
            }
        }
    }
    lds[wave][e0] = a00;
    lds[wave][e0 + 1] = a01;
    if (act30) {
        lds[wave][128 + e0] = a10;
        lds[wave][129 + e0] = a11;
    }
    __syncthreads();
    float u = (lane < 47)
                  ? 0.25f * (lds[wave][lane] + lds[wave][47 + lane] +
                             lds[wave][94 + lane] + lds[wave][141 + lane])
                  : -__builtin_inff();
    float mx = u;
#pragma unroll
    for (int o = 32; o > 0; o >>= 1) mx = fmaxf(mx, __shfl_xor(mx, o));
    float ex = (lane < 47) ? __expf(u - mx) : 0.f;
    float sm = ex;
#pragma unroll
    for (int o = 32; o > 0; o >>= 1) sm += __shfl_xor(sm, o);
    if (lane < 47) out[(size_t)n * 47 + lane] = u - mx - logf(sm);
}

// ---------------- launch ----------------

extern "C" void kernel_launch(void* const* d_in, const int* in_sizes, int n_in,
                              void* d_out, int out_size, void* d_ws, size_t ws_size,
                              hipStream_t stream) {
    const float* x = (const float*)d_in[0];
    const int* src = (const int*)d_in[1];
    const int* dst = (const int*)d_in[2];
    const float* W1 = (const float*)d_in[3];
    const float* al1 = (const float*)d_in[4];
    const float* ar1 = (const float*)d_in[5];
    const float* W2 = (const float*)d_in[6];
    const float* al2 = (const float*)d_in[7];
    const float* ar2 = (const float*)d_in[8];
    const float* W3 = (const float*)d_in[9];
    const float* al3 = (const float*)d_in[10];
    const float* ar3 = (const float*)d_in[11];
    float* out = (float*)d_out;

    char* p = (char*)d_ws;
    auto alloc = [&](size_t bytes) {
        char* r = p;
        p += (bytes + 255) & ~(size_t)255;
        return r;
    };
    u16* bufA = (u16*)alloc((size_t)N_NODES * 128 * 2);
    u16* bufC = (u16*)alloc((size_t)N_NODES * 128 * 2);
    u16* featb = (u16*)alloc((size_t)N_NODES * 192 * 2);
    float* el = (float*)alloc((size_t)N_NODES * NH * 4);
    float* er = (float*)alloc((size_t)N_NODES * NH * 4);
    u16* wp1 = (u16*)alloc((size_t)(256 / 32) * 8 * 512 * 2);
    u16* wp2 = (u16*)alloc((size_t)(128 / 32) * 8 * 512 * 2);
    u16* wp3 = (u16*)alloc((size_t)(128 / 32) * 12 * 512 * 2);
    int* deg = (int*)alloc((size_t)N_NODES * 4);
    int* offs = (int*)alloc((size_t)(N_NODES + 1) * 4);
    int* cursor = (int*)alloc((size_t)N_NODES * 4);
    int* bsum = (int*)alloc(64 * 4);
    int* csrc = (int*)alloc((size_t)N_EDGES * 4);

    // W pre-pack
    prep_w<256, 128, 128><<<(8 * 8 * 512 + 255) / 256, 256, 0, stream>>>(W1, wp1);
    prep_w<128, 128, 128><<<(4 * 8 * 512 + 255) / 256, 256, 0, stream>>>(W2, wp2);
    prep_w<128, 188, 192><<<(4 * 12 * 512 + 255) / 256, 256, 0, stream>>>(W3, wp3);

    // CSR by dst
    hipMemsetAsync(deg, 0, (size_t)N_NODES * 4, stream);
    k_hist<<<(N_EDGES + 255) / 256, 256, 0, stream>>>(dst, deg);
    k_scan1<<<49, 1024, 0, stream>>>(deg, offs, bsum);
    k_scan2<<<1, 64, 0, stream>>>(bsum, 49);
    k_scan3<<<49, 1024, 0, stream>>>(offs, bsum, cursor);
    k_scatter<<<(N_EDGES + 255) / 256, 256, 0, stream>>>(src, dst, cursor, csrc);

    int gemm_grid = (N_NODES + 63) / 64;
    // layer 1 (dots fused into GEMM; softmax fused into agg)
    gemm_mfma<256, 128, 128, true, true><<<gemm_grid, 256, 0, stream>>>(x, wp1, featb, al1, ar1, el, er);
    gat_agg128<<<N_NODES / 4, 256, 0, stream>>>(featb, el, er, offs, csrc, bufA);
    // layer 2
    gemm_mfma<128, 128, 128, false, true><<<gemm_grid, 256, 0, stream>>>(bufA, wp2, featb, al2, ar2, el, er);
    gat_agg128<<<N_NODES / 4, 256, 0, stream>>>(featb, el, er, offs, csrc, bufC);
    // layer 3 (dots separate: DH=47 not 16-aligned)
    gemm_mfma<128, 188, 192, false, false><<<gemm_grid, 256, 0, stream>>>(bufC, wp3, featb, nullptr, nullptr, nullptr, nullptr);
    attn_dots<47, 192><<<N_NODES / 4, 256, 0, stream>>>(featb, al3, ar3, el, er);
    gat_agg_final<<<N_NODES / 4, 256, 0, stream>>>(featb, el, er, offs, csrc, out);
}

// Round 10
// 314.095 us; speedup vs baseline: 1.3412x; 1.0699x over previous
//
#include <hip/hip_runtime.h>
#include <hip/hip_bf16.h>
#include <math.h>
#include <string.h>

#define N_NODES 50000
#define N_EDGES 800000
#define NH 4

typedef unsigned int u32;
typedef unsigned short u16;
typedef __attribute__((ext_vector_type(8))) short bf16x8;
typedef __attribute__((ext_vector_type(4))) float f32x4;

__device__ __forceinline__ u32 pack_bf2(float a, float b) {
    __hip_bfloat162 h2 = __float22bfloat162_rn(make_float2(a, b));
    u32 r;
    memcpy(&r, &h2, 4);
    return r;
}
__device__ __forceinline__ float2 bf2_to_f2(u32 u) {
    return make_float2(__uint_as_float(u << 16), __uint_as_float(u & 0xffff0000u));
}
__device__ __forceinline__ short bf16r(float f) {
    __hip_bfloat16 h = __float2bfloat16(f);
    short s;
    memcpy(&s, &h, 2);
    return s;
}

__device__ __forceinline__ float wred_max(float v) {
#pragma unroll
    for (int o = 32; o > 0; o >>= 1) v = fmaxf(v, __shfl_xor(v, o));
    return v;
}
__device__ __forceinline__ float wred_sum(float v) {
#pragma unroll
    for (int o = 32; o > 0; o >>= 1) v += __shfl_xor(v, o);
    return v;
}

// ---------------- CSR build ----------------

__global__ void k_hist(const int* __restrict__ dst, int* __restrict__ deg) {
    int i = blockIdx.x * 256 + threadIdx.x;
    if (i < N_EDGES) atomicAdd(&deg[dst[i]], 1);
}

__global__ __launch_bounds__(1024) void k_scan1(const int* __restrict__ deg,
                                                int* __restrict__ offs,
                                                int* __restrict__ bsum) {
    __shared__ int tmp[1024];
    int b = blockIdx.x, t = threadIdx.x;
    int i = b * 1024 + t;
    int v = (i < N_NODES) ? deg[i] : 0;
    tmp[t] = v;
    __syncthreads();
    for (int off = 1; off < 1024; off <<= 1) {
        int add = (t >= off) ? tmp[t - off] : 0;
        __syncthreads();
        tmp[t] += add;
        __syncthreads();
    }
    if (i < N_NODES) offs[i] = tmp[t] - v;
    if (t == 1023) bsum[b] = tmp[t];
}

__global__ void k_scan2(int* __restrict__ bsum, int nb) {
    if (blockIdx.x == 0 && threadIdx.x == 0) {
        int run = 0;
        for (int b = 0; b < nb; ++b) { int v = bsum[b]; bsum[b] = run; run += v; }
    }
}

__global__ __launch_bounds__(1024) void k_scan3(int* __restrict__ offs,
                                                const int* __restrict__ bsum,
                                                int* __restrict__ cursor) {
    int b = blockIdx.x, t = threadIdx.x;
    int i = b * 1024 + t;
    if (i < N_NODES) {
        int o = offs[i] + bsum[b];
        offs[i] = o;
        cursor[i] = o;
    }
    if (b == 0 && t == 0) offs[N_NODES] = N_EDGES;
}

__global__ void k_scatter(const int* __restrict__ src, const int* __restrict__ dst,
                          int* __restrict__ cursor, int* __restrict__ csrc) {
    int i = blockIdx.x * 256 + threadIdx.x;
    if (i < N_EDGES) {
        int p = atomicAdd(&cursor[dst[i]], 1);
        csrc[p] = src[i];
    }
}

// ---------------- W pre-pack into MFMA B-fragment layout ----------------
template <int K, int NOUT, int NP>
__global__ void prep_w(const float* __restrict__ W, u16* __restrict__ Wp) {
    constexpr int NT = NP / 16;
    int idx = blockIdx.x * 256 + threadIdx.x;
    int total = (K / 32) * NT * 64 * 8;
    if (idx >= total) return;
    int j = idx & 7;
    int lane = (idx >> 3) & 63;
    int rest = idx >> 9;
    int nt = rest % NT;
    int kt = rest / NT;
    int k = kt * 32 + (lane >> 4) * 8 + j;
    int col = nt * 16 + (lane & 15);
    float v = (col < NOUT) ? W[(size_t)k * NOUT + col] : 0.f;
    Wp[idx] = (u16)bf16r(v);
}

// layer-3 pre-pack with head-major-48 padded output layout:
// padded col c -> head h=c/48, dim d=c%48; real if d<47 -> W col h*47+d; pad col -> 0
template <int K>
__global__ void prep_w3(const float* __restrict__ W, u16* __restrict__ Wp) {
    constexpr int NT = 12;
    int idx = blockIdx.x * 256 + threadIdx.x;
    int total = (K / 32) * NT * 64 * 8;
    if (idx >= total) return;
    int j = idx & 7;
    int lane = (idx >> 3) & 63;
    int rest = idx >> 9;
    int nt = rest % NT;
    int kt = rest / NT;
    int k = kt * 32 + (lane >> 4) * 8 + j;
    int col = nt * 16 + (lane & 15);
    int h = col / 48, d = col % 48;
    float v = (d < 47) ? W[(size_t)k * 188 + h * 47 + d] : 0.f;
    Wp[idx] = (u16)bf16r(v);
}

// ---------------- MFMA GEMM: feat(bf16,[N,NP]) = A @ W (+fused attn dots) ----------------
// HEADPAD: NP=192 head-major-48 layout; al/ar remapped from [4][47].
template <int K, int NOUT, int NP, bool AF32, bool DOTS, bool HEADPAD>
__global__ __launch_bounds__(256) void gemm_mfma(const void* __restrict__ Av,
                                                 const u16* __restrict__ Wp,
                                                 u16* __restrict__ feat,
                                                 const float* __restrict__ al,
                                                 const float* __restrict__ ar,
                                                 float* __restrict__ el,
                                                 float* __restrict__ er) {
    constexpr int NT = NP / 16;
    constexpr int KT = K / 32;
    int w = threadIdx.x >> 6, l = threadIdx.x & 63;
    int tile_m0 = blockIdx.x * 64 + w * 16;
    int c15 = l & 15;
    int rowA = tile_m0 + c15;
    if (rowA >= N_NODES) rowA = N_NODES - 1;
    int g = l >> 4;

    f32x4 acc[NT];
#pragma unroll
    for (int nt = 0; nt < NT; ++nt) acc[nt] = (f32x4){0.f, 0.f, 0.f, 0.f};

    for (int kt = 0; kt < KT; ++kt) {
        bf16x8 a;
        if constexpr (AF32) {
            const float* ap = (const float*)Av + (size_t)rowA * K + kt * 32 + g * 8;
            float4 f0 = *reinterpret_cast<const float4*>(ap);
            float4 f1 = *reinterpret_cast<const float4*>(ap + 4);
            a[0] = bf16r(f0.x); a[1] = bf16r(f0.y); a[2] = bf16r(f0.z); a[3] = bf16r(f0.w);
            a[4] = bf16r(f1.x); a[5] = bf16r(f1.y); a[6] = bf16r(f1.z); a[7] = bf16r(f1.w);
        } else {
            a = *reinterpret_cast<const bf16x8*>((const u16*)Av + (size_t)rowA * K + kt * 32 + g * 8);
        }
        const u16* wp = Wp + ((size_t)kt * NT) * 512 + (size_t)l * 8;
#pragma unroll
        for (int nt = 0; nt < NT; ++nt) {
            bf16x8 b = *reinterpret_cast<const bf16x8*>(wp + nt * 512);
            acc[nt] = __builtin_amdgcn_mfma_f32_16x16x32_bf16(a, b, acc[nt], 0, 0, 0);
        }
    }

    int rowD0 = tile_m0 + g * 4;
#pragma unroll
    for (int nt = 0; nt < NT; ++nt) {
        int col = nt * 16 + c15;
#pragma unroll
        for (int r = 0; r < 4; ++r) {
            int row = rowD0 + r;
            if (row < N_NODES)
                feat[(size_t)row * NP + col] = (u16)bf16r(acc[nt][r]);
        }
    }

    if constexpr (DOTS) {
        float alv[NT], arv[NT];
#pragma unroll
        for (int nt = 0; nt < NT; ++nt) {
            if constexpr (HEADPAD) {
                int h = nt / 3, m = nt % 3;
                if (m == 2) {
                    alv[nt] = (c15 < 15) ? al[h * 47 + 32 + c15] : 0.f;
                    arv[nt] = (c15 < 15) ? ar[h * 47 + 32 + c15] : 0.f;
                } else {
                    alv[nt] = al[h * 47 + m * 16 + c15];
                    arv[nt] = ar[h * 47 + m * 16 + c15];
                }
            } else {
                alv[nt] = al[nt * 16 + c15];
                arv[nt] = ar[nt * 16 + c15];
            }
        }
#pragma unroll
        for (int r = 0; r < 4; ++r) {
            float hlv[NH] = {0.f, 0.f, 0.f, 0.f};
            float hrv[NH] = {0.f, 0.f, 0.f, 0.f};
#pragma unroll
            for (int nt = 0; nt < NT; ++nt) {
                constexpr int NTH = NT / NH;
                int h = nt / NTH;
                hlv[h] = fmaf(acc[nt][r], alv[nt], hlv[h]);
                hrv[h] = fmaf(acc[nt][r], arv[nt], hrv[h]);
            }
#pragma unroll
            for (int o = 1; o < 16; o <<= 1) {
#pragma unroll
                for (int j = 0; j < NH; ++j) {
                    hlv[j] += __shfl_xor(hlv[j], o);
                    hrv[j] += __shfl_xor(hrv[j], o);
                }
            }
            int row = rowD0 + r;
            if (c15 == 0 && row < N_NODES) {
                *reinterpret_cast<float4*>(el + (size_t)row * NH) =
                    make_float4(hlv[0], hlv[1], hlv[2], hlv[3]);
                *reinterpret_cast<float4*>(er + (size_t)row * NH) =
                    make_float4(hrv[0], hrv[1], hrv[2], hrv[3]);
            }
        }
    }
}

// ---------------- per-chunk alpha -> LDS (transposed) ----------------
// writes lalT[h][lane] (h-major) and lsrc[lane] for edges [base, min(base+64,i1))
__device__ __forceinline__ void alpha_chunk_T(const float* __restrict__ el,
                                              const int* __restrict__ csrc,
                                              float4 erv, int base, int i1,
                                              float4 mref, float4 vinv, bool online,
                                              float* __restrict__ lalT,
                                              int* __restrict__ lsrc, int lane) {
    int e = base + lane;
    bool act = e < i1;
    int srcn = act ? csrc[e] : 0;
    float4 elv = make_float4(0.f, 0.f, 0.f, 0.f);
    if (act) elv = *reinterpret_cast<const float4*>(el + (size_t)srcn * NH);
    float e0 = elv.x + erv.x; e0 = e0 >= 0.f ? e0 : 0.2f * e0;
    float e1 = elv.y + erv.y; e1 = e1 >= 0.f ? e1 : 0.2f * e1;
    float e2 = elv.z + erv.z; e2 = e2 >= 0.f ? e2 : 0.2f * e2;
    float e3 = elv.w + erv.w; e3 = e3 >= 0.f ? e3 : 0.2f * e3;
    float4 a4;
    if (online) {
        const float NEG = -__builtin_inff();
        float f0 = act ? e0 : NEG, f1 = act ? e1 : NEG, f2 = act ? e2 : NEG, f3 = act ? e3 : NEG;
        float m0 = wred_max(f0), m1 = wred_max(f1), m2 = wred_max(f2), m3 = wred_max(f3);
        float p0 = act ? __expf(e0 - m0) : 0.f;
        float p1 = act ? __expf(e1 - m1) : 0.f;
        float p2 = act ? __expf(e2 - m2) : 0.f;
        float p3 = act ? __expf(e3 - m3) : 0.f;
        float s0 = wred_sum(p0), s1 = wred_sum(p1), s2 = wred_sum(p2), s3 = wred_sum(p3);
        a4 = make_float4(act ? p0 / s0 : 0.f, act ? p1 / s1 : 0.f,
                         act ? p2 / s2 : 0.f, act ? p3 / s3 : 0.f);
    } else {
        a4 = make_float4(act ? __expf(e0 - mref.x) * vinv.x : 0.f,
                         act ? __expf(e1 - mref.y) * vinv.y : 0.f,
                         act ? __expf(e2 - mref.z) * vinv.z : 0.f,
                         act ? __expf(e3 - mref.w) * vinv.w : 0.f);
    }
    lalT[0 * 64 + lane] = a4.x;
    lalT[1 * 64 + lane] = a4.y;
    lalT[2 * 64 + lane] = a4.z;
    lalT[3 * 64 + lane] = a4.w;
    lsrc[lane] = srcn;
}

// global-stats pass for deg>64 nodes
__device__ __forceinline__ void stats_pass(const float* __restrict__ el,
                                           const int* __restrict__ csrc,
                                           float4 erv, int i0, int i1, int lane,
                                           float4& mout, float4& vout) {
    const float NEG = -__builtin_inff();
    float m0 = NEG, m1 = NEG, m2 = NEG, m3 = NEG;
    float s0 = 0.f, s1 = 0.f, s2 = 0.f, s3 = 0.f;
    for (int base = i0; base < i1; base += 64) {
        int i = base + lane;
        bool act = i < i1;
        int srcn = act ? csrc[i] : 0;
        float4 elv = make_float4(0.f, 0.f, 0.f, 0.f);
        if (act) elv = *reinterpret_cast<const float4*>(el + (size_t)srcn * NH);
        float e0 = elv.x + erv.x; e0 = e0 >= 0.f ? e0 : 0.2f * e0;
        float e1 = elv.y + erv.y; e1 = e1 >= 0.f ? e1 : 0.2f * e1;
        float e2 = elv.z + erv.z; e2 = e2 >= 0.f ? e2 : 0.2f * e2;
        float e3 = elv.w + erv.w; e3 = e3 >= 0.f ? e3 : 0.2f * e3;
        if (!act) { e0 = NEG; e1 = NEG; e2 = NEG; e3 = NEG; }
        float c0 = wred_max(e0), c1 = wred_max(e1), c2 = wred_max(e2), c3 = wred_max(e3);
        float nm0 = fmaxf(m0, c0), nm1 = fmaxf(m1, c1), nm2 = fmaxf(m2, c2), nm3 = fmaxf(m3, c3);
        float p0 = act ? __expf(e0 - nm0) : 0.f;
        float p1 = act ? __expf(e1 - nm1) : 0.f;
        float p2 = act ? __expf(e2 - nm2) : 0.f;
        float p3 = act ? __expf(e3 - nm3) : 0.f;
        float S0 = wred_sum(p0), S1 = wred_sum(p1), S2 = wred_sum(p2), S3 = wred_sum(p3);
        s0 = s0 * __expf(m0 - nm0) + S0; m0 = nm0;
        s1 = s1 * __expf(m1 - nm1) + S1; m1 = nm1;
        s2 = s2 * __expf(m2 - nm2) + S2; m2 = nm2;
        s3 = s3 * __expf(m3 - nm3) + S3; m3 = nm3;
    }
    mout = make_float4(m0, m1, m2, m3);
    vout = make_float4(1.f / s0, 1.f / s1, 1.f / s2, 1.f / s3);
}

// ---------------- fused softmax+aggregation, layers 1-2 (128 cols) ----------------
__global__ __launch_bounds__(256) void gat_agg128(const u16* __restrict__ feat,
                                                  const float* __restrict__ el,
                                                  const float* __restrict__ er,
                                                  const int* __restrict__ offs,
                                                  const int* __restrict__ csrc,
                                                  u16* __restrict__ out) {
    __shared__ float lalT[4][4][64];
    __shared__ int lsrc[4][64];
    int wave = threadIdx.x >> 6;
    int lane = threadIdx.x & 63;
    int n = blockIdx.x * 4 + wave;
    int h = lane >> 4;
    int i0 = offs[n], i1 = offs[n + 1];
    int d = i1 - i0;
    float ax = 0.f, ay = 0.f;
    if (d > 0) {
        float4 erv = *reinterpret_cast<const float4*>(er + (size_t)n * NH);
        float4 mref = make_float4(0.f, 0.f, 0.f, 0.f), vinv = mref;
        bool onechunk = d <= 64;
        if (!onechunk) stats_pass(el, csrc, erv, i0, i1, lane, mref, vinv);
        for (int base = i0; base < i1; base += 64) {
            alpha_chunk_T(el, csrc, erv, base, i1, mref, vinv, onechunk,
                          &lalT[wave][0][0], &lsrc[wave][0], lane);
            int cnt = i1 - base; if (cnt > 64) cnt = 64;
            int cpad = (cnt + 3) & ~3;
            for (int j = 0; j < cpad; j += 4) {
                int4 sv = *reinterpret_cast<const int4*>(&lsrc[wave][j]);
                float4 aq = *reinterpret_cast<const float4*>(&lalT[wave][h][j]);
                u32 q0 = *reinterpret_cast<const u32*>(feat + (size_t)sv.x * 128 + 2 * lane);
                u32 q1 = *reinterpret_cast<const u32*>(feat + (size_t)sv.y * 128 + 2 * lane);
                u32 q2 = *reinterpret_cast<const u32*>(feat + (size_t)sv.z * 128 + 2 * lane);
                u32 q3 = *reinterpret_cast<const u32*>(feat + (size_t)sv.w * 128 + 2 * lane);
                float2 v;
                v = bf2_to_f2(q0); ax = fmaf(aq.x, v.x, ax); ay = fmaf(aq.x, v.y, ay);
                v = bf2_to_f2(q1); ax = fmaf(aq.y, v.x, ax); ay = fmaf(aq.y, v.y, ay);
                v = bf2_to_f2(q2); ax = fmaf(aq.z, v.x, ax); ay = fmaf(aq.z, v.y, ay);
                v = bf2_to_f2(q3); ax = fmaf(aq.w, v.x, ax); ay = fmaf(aq.w, v.y, ay);
            }
        }
    }
    float ox = ax > 0.f ? ax : expm1f(ax);
    float oy = ay > 0.f ? ay : expm1f(ay);
    *reinterpret_cast<u32*>(out + (size_t)n * 128 + 2 * lane) = pack_bf2(ox, oy);
}

// ---------------- fused softmax+aggregation, layer 3 (192-col head-major-48) ----------------
__global__ __launch_bounds__(256) void gat_agg_final(const u16* __restrict__ feat,
                                                     const float* __restrict__ el,
                                                     const float* __restrict__ er,
                                                     const int* __restrict__ offs,
                                                     const int* __restrict__ csrc,
                                                     float* __restrict__ out) {
    __shared__ float lalT[4][4][64];
    __shared__ int lsrc[4][64];
    __shared__ float lds[4][192];
    int wave = threadIdx.x >> 6;
    int lane = threadIdx.x & 63;
    int n = blockIdx.x * 4 + wave;
    int e0 = 2 * lane;
    bool up = lane < 32;                 // upper half: cols 128+e0, 129+e0 (<=191)
    int hLo = e0 / 48;                   // pairs never straddle heads (48 even)
    int hHi = up ? (128 + e0) / 48 : 3;
    int i0 = offs[n], i1 = offs[n + 1];
    int d = i1 - i0;
    float a00 = 0.f, a01 = 0.f, a10 = 0.f, a11 = 0.f;
    if (d > 0) {
        float4 erv = *reinterpret_cast<const float4*>(er + (size_t)n * NH);
        float4 mref = make_float4(0.f, 0.f, 0.f, 0.f), vinv = mref;
        bool onechunk = d <= 64;
        if (!onechunk) stats_pass(el, csrc, erv, i0, i1, lane, mref, vinv);
        for (int base = i0; base < i1; base += 64) {
            alpha_chunk_T(el, csrc, erv, base, i1, mref, vinv, onechunk,
                          &lalT[wave][0][0], &lsrc[wave][0], lane);
            int cnt = i1 - base; if (cnt > 64) cnt = 64;
            int cpad = (cnt + 3) & ~3;
            for (int j = 0; j < cpad; j += 4) {
                int4 sv = *reinterpret_cast<const int4*>(&lsrc[wave][j]);
                float4 wlo = *reinterpret_cast<const float4*>(&lalT[wave][hLo][j]);
                float4 whi = *reinterpret_cast<const float4*>(&lalT[wave][hHi][j]);
                const u16* rA = feat + (size_t)sv.x * 192;
                const u16* rB = feat + (size_t)sv.y * 192;
                const u16* rC = feat + (size_t)sv.z * 192;
                const u16* rD = feat + (size_t)sv.w * 192;
                u32 a0 = *reinterpret_cast<const u32*>(rA + e0);
                u32 b0 = *reinterpret_cast<const u32*>(rB + e0);
                u32 c0 = *reinterpret_cast<const u32*>(rC + e0);
                u32 d0 = *reinterpret_cast<const u32*>(rD + e0);
                u32 a1 = up ? *reinterpret_cast<const u32*>(rA + 128 + e0) : 0u;
                u32 b1 = up ? *reinterpret_cast<const u32*>(rB + 128 + e0) : 0u;
                u32 c1 = up ? *reinterpret_cast<const u32*>(rC + 128 + e0) : 0u;
                u32 d1 = up ? *reinterpret_cast<const u32*>(rD + 128 + e0) : 0u;
                float2 v;
                v = bf2_to_f2(a0); a00 = fmaf(wlo.x, v.x, a00); a01 = fmaf(wlo.x, v.y, a01);
                v = bf2_to_f2(b0); a00 = fmaf(wlo.y, v.x, a00); a01 = fmaf(wlo.y, v.y, a01);
                v = bf2_to_f2(c0); a00 = fmaf(wlo.z, v.x, a00); a01 = fmaf(wlo.z, v.y, a01);
                v = bf2_to_f2(d0); a00 = fmaf(wlo.w, v.x, a00); a01 = fmaf(wlo.w, v.y, a01);
                v = bf2_to_f2(a1); a10 = fmaf(whi.x, v.x, a10); a11 = fmaf(whi.x, v.y, a11);
                v = bf2_to_f2(b1); a10 = fmaf(whi.y, v.x, a10); a11 = fmaf(whi.y, v.y, a11);
                v = bf2_to_f2(c1); a10 = fmaf(whi.z, v.x, a10); a11 = fmaf(whi.z, v.y, a11);
                v = bf2_to_f2(d1); a10 = fmaf(whi.w, v.x, a10); a11 = fmaf(whi.w, v.y, a11);
            }
        }
    }
    lds[wave][e0] = a00;
    lds[wave][e0 + 1] = a01;
    if (up) {
        lds[wave][128 + e0] = a10;
        lds[wave][129 + e0] = a11;
    }
    __syncthreads();
    // head-major-48 layout: head h dim l at col 48h+l
    float u = (lane < 47)
                  ? 0.25f * (lds[wave][lane] + lds[wave][48 + lane] +
                             lds[wave][96 + lane] + lds[wave][144 + lane])
                  : -__builtin_inff();
    float mx = u;
#pragma unroll
    for (int o = 32; o > 0; o >>= 1) mx = fmaxf(mx, __shfl_xor(mx, o));
    float ex = (lane < 47) ? __expf(u - mx) : 0.f;
    float sm = ex;
#pragma unroll
    for (int o = 32; o > 0; o >>= 1) sm += __shfl_xor(sm, o);
    if (lane < 47) out[(size_t)n * 47 + lane] = u - mx - logf(sm);
}

// ---------------- launch ----------------

extern "C" void kernel_launch(void* const* d_in, const int* in_sizes, int n_in,
                              void* d_out, int out_size, void* d_ws, size_t ws_size,
                              hipStream_t stream) {
    const float* x = (const float*)d_in[0];
    const int* src = (const int*)d_in[1];
    const int* dst = (const int*)d_in[2];
    const float* W1 = (const float*)d_in[3];
    const float* al1 = (const float*)d_in[4];
    const float* ar1 = (const float*)d_in[5];
    const float* W2 = (const float*)d_in[6];
    const float* al2 = (const float*)d_in[7];
    const float* ar2 = (const float*)d_in[8];
    const float* W3 = (const float*)d_in[9];
    const float* al3 = (const float*)d_in[10];
    const float* ar3 = (const float*)d_in[11];
    float* out = (float*)d_out;

    char* p = (char*)d_ws;
    auto alloc = [&](size_t bytes) {
        char* r = p;
        p += (bytes + 255) & ~(size_t)255;
        return r;
    };
    u16* bufA = (u16*)alloc((size_t)N_NODES * 128 * 2);
    u16* bufC = (u16*)alloc((size_t)N_NODES * 128 * 2);
    u16* featb = (u16*)alloc((size_t)N_NODES * 192 * 2);
    float* el = (float*)alloc((size_t)N_NODES * NH * 4);
    float* er = (float*)alloc((size_t)N_NODES * NH * 4);
    u16* wp1 = (u16*)alloc((size_t)(256 / 32) * 8 * 512 * 2);
    u16* wp2 = (u16*)alloc((size_t)(128 / 32) * 8 * 512 * 2);
    u16* wp3 = (u16*)alloc((size_t)(128 / 32) * 12 * 512 * 2);
    int* deg = (int*)alloc((size_t)N_NODES * 4);
    int* offs = (int*)alloc((size_t)(N_NODES + 1) * 4);
    int* cursor = (int*)alloc((size_t)N_NODES * 4);
    int* bsum = (int*)alloc(64 * 4);
    int* csrc = (int*)alloc((size_t)N_EDGES * 4);

    // W pre-pack
    prep_w<256, 128, 128><<<(8 * 8 * 512 + 255) / 256, 256, 0, stream>>>(W1, wp1);
    prep_w<128, 128, 128><<<(4 * 8 * 512 + 255) / 256, 256, 0, stream>>>(W2, wp2);
    prep_w3<128><<<(4 * 12 * 512 + 255) / 256, 256, 0, stream>>>(W3, wp3);

    // CSR by dst
    hipMemsetAsync(deg, 0, (size_t)N_NODES * 4, stream);
    k_hist<<<(N_EDGES + 255) / 256, 256, 0, stream>>>(dst, deg);
    k_scan1<<<49, 1024, 0, stream>>>(deg, offs, bsum);
    k_scan2<<<1, 64, 0, stream>>>(bsum, 49);
    k_scan3<<<49, 1024, 0, stream>>>(offs, bsum, cursor);
    k_scatter<<<(N_EDGES + 255) / 256, 256, 0, stream>>>(src, dst, cursor, csrc);

    int gemm_grid = (N_NODES + 63) / 64;
    // layer 1 (dots fused into GEMM; softmax fused into agg)
    gemm_mfma<256, 128, 128, true, true, false><<<gemm_grid, 256, 0, stream>>>(x, wp1, featb, al1, ar1, el, er);
    gat_agg128<<<N_NODES / 4, 256, 0, stream>>>(featb, el, er, offs, csrc, bufA);
    // layer 2
    gemm_mfma<128, 128, 128, false, true, false><<<gemm_grid, 256, 0, stream>>>(bufA, wp2, featb, al2, ar2, el, er);
    gat_agg128<<<N_NODES / 4, 256, 0, stream>>>(featb, el, er, offs, csrc, bufC);
    // layer 3 (head-major-48 padded layout; dots fused too)
    gemm_mfma<128, 192, 192, false, true, true><<<gemm_grid, 256, 0, stream>>>(bufC, wp3, featb, al3, ar3, el, er);
    gat_agg_final<<<N_NODES / 4, 256, 0, stream>>>(featb, el, er, offs, csrc, out);
}

// Round 11
// 302.806 us; speedup vs baseline: 1.3912x; 1.0373x over previous
//
#include <hip/hip_runtime.h>
#include <hip/hip_bf16.h>
#include <math.h>
#include <string.h>

#define N_NODES 50000
#define N_EDGES 800000
#define NH 4
#define LSTR 136   // padded lalT stride (floats): head groups land 8 banks apart

typedef unsigned int u32;
typedef unsigned short u16;
typedef __attribute__((ext_vector_type(8))) short bf16x8;
typedef __attribute__((ext_vector_type(4))) float f32x4;
typedef __attribute__((ext_vector_type(2))) float f32x2;

__device__ __forceinline__ u32 pack_bf2(float a, float b) {
    __hip_bfloat162 h2 = __float22bfloat162_rn(make_float2(a, b));
    u32 r;
    memcpy(&r, &h2, 4);
    return r;
}
__device__ __forceinline__ f32x2 bf2_to_v2(u32 u) {
    f32x2 v;
    v.x = __uint_as_float(u << 16);
    v.y = __uint_as_float(u & 0xffff0000u);
    return v;
}
__device__ __forceinline__ short bf16r(float f) {
    __hip_bfloat16 h = __float2bfloat16(f);
    short s;
    memcpy(&s, &h, 2);
    return s;
}
// acc += a * b (packed 2x f32)
__device__ __forceinline__ void pkfma(f32x2& acc, f32x2 a, f32x2 b) {
    asm("v_pk_fma_f32 %0, %1, %2, %0" : "+v"(acc) : "v"(a), "v"(b));
}

__device__ __forceinline__ float wred_max(float v) {
#pragma unroll
    for (int o = 32; o > 0; o >>= 1) v = fmaxf(v, __shfl_xor(v, o));
    return v;
}
__device__ __forceinline__ float wred_sum(float v) {
#pragma unroll
    for (int o = 32; o > 0; o >>= 1) v += __shfl_xor(v, o);
    return v;
}

// ---------------- CSR build ----------------

__global__ void k_hist(const int* __restrict__ dst, int* __restrict__ deg) {
    int i = blockIdx.x * 256 + threadIdx.x;
    if (i < N_EDGES) atomicAdd(&deg[dst[i]], 1);
}

__global__ __launch_bounds__(1024) void k_scan1(const int* __restrict__ deg,
                                                int* __restrict__ offs,
                                                int* __restrict__ bsum) {
    __shared__ int tmp[1024];
    int b = blockIdx.x, t = threadIdx.x;
    int i = b * 1024 + t;
    int v = (i < N_NODES) ? deg[i] : 0;
    tmp[t] = v;
    __syncthreads();
    for (int off = 1; off < 1024; off <<= 1) {
        int add = (t >= off) ? tmp[t - off] : 0;
        __syncthreads();
        tmp[t] += add;
        __syncthreads();
    }
    if (i < N_NODES) offs[i] = tmp[t] - v;
    if (t == 1023) bsum[b] = tmp[t];
}

// wave-parallel exclusive scan of bsum (nb <= 64)
__global__ void k_scan2(int* __restrict__ bsum, int nb) {
    int t = threadIdx.x & 63;
    int v = (t < nb) ? bsum[t] : 0;
    int orig = v;
#pragma unroll
    for (int o = 1; o < 64; o <<= 1) {
        int u = __shfl_up(v, o);
        if (t >= o) v += u;
    }
    if (t < nb) bsum[t] = v - orig;
}

__global__ __launch_bounds__(1024) void k_scan3(int* __restrict__ offs,
                                                const int* __restrict__ bsum,
                                                int* __restrict__ cursor) {
    int b = blockIdx.x, t = threadIdx.x;
    int i = b * 1024 + t;
    if (i < N_NODES) {
        int o = offs[i] + bsum[b];
        offs[i] = o;
        cursor[i] = o;
    }
    if (b == 0 && t == 0) offs[N_NODES] = N_EDGES;
}

__global__ void k_scatter(const int* __restrict__ src, const int* __restrict__ dst,
                          int* __restrict__ cursor, int* __restrict__ csrc) {
    int i = blockIdx.x * 256 + threadIdx.x;
    if (i < N_EDGES) {
        int p = atomicAdd(&cursor[dst[i]], 1);
        csrc[p] = src[i];
    }
}

// ---------------- fused W pre-pack (all 3 layers, one dispatch) ----------------
__device__ __forceinline__ u16 pack_elem(const float* W, int i, int K, int NT, int NOUT) {
    int j = i & 7;
    int lane = (i >> 3) & 63;
    int rest = i >> 9;
    int nt = rest % NT;
    int kt = rest / NT;
    int k = kt * 32 + (lane >> 4) * 8 + j;
    int col = nt * 16 + (lane & 15);
    float v = (col < NOUT) ? W[(size_t)k * NOUT + col] : 0.f;
    return (u16)bf16r(v);
}
__device__ __forceinline__ u16 pack_elem3(const float* W, int i) {
    // K=128, NT=12, head-major-48 padded: col c -> head c/48, dim c%48 (pad d=47 -> 0)
    int j = i & 7;
    int lane = (i >> 3) & 63;
    int rest = i >> 9;
    int nt = rest % 12;
    int kt = rest / 12;
    int k = kt * 32 + (lane >> 4) * 8 + j;
    int col = nt * 16 + (lane & 15);
    int h = col / 48, d = col % 48;
    float v = (d < 47) ? W[(size_t)k * 188 + h * 47 + d] : 0.f;
    return (u16)bf16r(v);
}
__global__ void prep_all(const float* __restrict__ W1, const float* __restrict__ W2,
                         const float* __restrict__ W3, u16* __restrict__ wp1,
                         u16* __restrict__ wp2, u16* __restrict__ wp3) {
    int idx = blockIdx.x * 256 + threadIdx.x;
    if (idx < 32768) {
        wp1[idx] = pack_elem(W1, idx, 256, 8, 128);
    } else if (idx < 49152) {
        int i = idx - 32768;
        wp2[i] = pack_elem(W2, i, 128, 8, 128);
    } else if (idx < 73728) {
        int i = idx - 49152;
        wp3[i] = pack_elem3(W3, i);
    }
}

// ---------------- MFMA GEMM: feat(bf16,[N,NP]) = A @ W (+fused attn dots) ----------------
template <int K, int NOUT, int NP, bool AF32, bool DOTS, bool HEADPAD>
__global__ __launch_bounds__(256) void gemm_mfma(const void* __restrict__ Av,
                                                 const u16* __restrict__ Wp,
                                                 u16* __restrict__ feat,
                                                 const float* __restrict__ al,
                                                 const float* __restrict__ ar,
                                                 float* __restrict__ el,
                                                 float* __restrict__ er) {
    constexpr int NT = NP / 16;
    constexpr int KT = K / 32;
    int w = threadIdx.x >> 6, l = threadIdx.x & 63;
    int tile_m0 = blockIdx.x * 64 + w * 16;
    int c15 = l & 15;
    int rowA = tile_m0 + c15;
    if (rowA >= N_NODES) rowA = N_NODES - 1;
    int g = l >> 4;

    f32x4 acc[NT];
#pragma unroll
    for (int nt = 0; nt < NT; ++nt) acc[nt] = (f32x4){0.f, 0.f, 0.f, 0.f};

    for (int kt = 0; kt < KT; ++kt) {
        bf16x8 a;
        if constexpr (AF32) {
            const float* ap = (const float*)Av + (size_t)rowA * K + kt * 32 + g * 8;
            float4 f0 = *reinterpret_cast<const float4*>(ap);
            float4 f1 = *reinterpret_cast<const float4*>(ap + 4);
            a[0] = bf16r(f0.x); a[1] = bf16r(f0.y); a[2] = bf16r(f0.z); a[3] = bf16r(f0.w);
            a[4] = bf16r(f1.x); a[5] = bf16r(f1.y); a[6] = bf16r(f1.z); a[7] = bf16r(f1.w);
        } else {
            a = *reinterpret_cast<const bf16x8*>((const u16*)Av + (size_t)rowA * K + kt * 32 + g * 8);
        }
        const u16* wp = Wp + ((size_t)kt * NT) * 512 + (size_t)l * 8;
#pragma unroll
        for (int nt = 0; nt < NT; ++nt) {
            bf16x8 b = *reinterpret_cast<const bf16x8*>(wp + nt * 512);
            acc[nt] = __builtin_amdgcn_mfma_f32_16x16x32_bf16(a, b, acc[nt], 0, 0, 0);
        }
    }

    int rowD0 = tile_m0 + g * 4;
#pragma unroll
    for (int nt = 0; nt < NT; ++nt) {
        int col = nt * 16 + c15;
#pragma unroll
        for (int r = 0; r < 4; ++r) {
            int row = rowD0 + r;
            if (row < N_NODES)
                feat[(size_t)row * NP + col] = (u16)bf16r(acc[nt][r]);
        }
    }

    if constexpr (DOTS) {
        float alv[NT], arv[NT];
#pragma unroll
        for (int nt = 0; nt < NT; ++nt) {
            if constexpr (HEADPAD) {
                int h = nt / 3, m = nt % 3;
                if (m == 2) {
                    alv[nt] = (c15 < 15) ? al[h * 47 + 32 + c15] : 0.f;
                    arv[nt] = (c15 < 15) ? ar[h * 47 + 32 + c15] : 0.f;
                } else {
                    alv[nt] = al[h * 47 + m * 16 + c15];
                    arv[nt] = ar[h * 47 + m * 16 + c15];
                }
            } else {
                alv[nt] = al[nt * 16 + c15];
                arv[nt] = ar[nt * 16 + c15];
            }
        }
#pragma unroll
        for (int r = 0; r < 4; ++r) {
            float hlv[NH] = {0.f, 0.f, 0.f, 0.f};
            float hrv[NH] = {0.f, 0.f, 0.f, 0.f};
#pragma unroll
            for (int nt = 0; nt < NT; ++nt) {
                constexpr int NTH = NT / NH;
                int h = nt / NTH;
                hlv[h] = fmaf(acc[nt][r], alv[nt], hlv[h]);
                hrv[h] = fmaf(acc[nt][r], arv[nt], hrv[h]);
            }
#pragma unroll
            for (int o = 1; o < 16; o <<= 1) {
#pragma unroll
                for (int j = 0; j < NH; ++j) {
                    hlv[j] += __shfl_xor(hlv[j], o);
                    hrv[j] += __shfl_xor(hrv[j], o);
                }
            }
            int row = rowD0 + r;
            if (c15 == 0 && row < N_NODES) {
                *reinterpret_cast<float4*>(el + (size_t)row * NH) =
                    make_float4(hlv[0], hlv[1], hlv[2], hlv[3]);
                *reinterpret_cast<float4*>(er + (size_t)row * NH) =
                    make_float4(hrv[0], hrv[1], hrv[2], hrv[3]);
            }
        }
    }
}

// ---------------- per-chunk alpha -> LDS (transposed, DUPLICATED pairs) ----------------
// lalT[h][2*lane] = lalT[h][2*lane+1] = alpha_h(edge base+lane); lsrc[lane] = src
__device__ __forceinline__ void alpha_chunk_T(const float* __restrict__ el,
                                              const int* __restrict__ csrc,
                                              float4 erv, int base, int i1,
                                              float4 mref, float4 vinv, bool online,
                                              float* __restrict__ lalT,
                                              int* __restrict__ lsrc, int lane) {
    int e = base + lane;
    bool act = e < i1;
    int srcn = act ? csrc[e] : 0;
    float4 elv = make_float4(0.f, 0.f, 0.f, 0.f);
    if (act) elv = *reinterpret_cast<const float4*>(el + (size_t)srcn * NH);
    float e0 = elv.x + erv.x; e0 = e0 >= 0.f ? e0 : 0.2f * e0;
    float e1 = elv.y + erv.y; e1 = e1 >= 0.f ? e1 : 0.2f * e1;
    float e2 = elv.z + erv.z; e2 = e2 >= 0.f ? e2 : 0.2f * e2;
    float e3 = elv.w + erv.w; e3 = e3 >= 0.f ? e3 : 0.2f * e3;
    float4 a4;
    if (online) {
        const float NEG = -__builtin_inff();
        float f0 = act ? e0 : NEG, f1 = act ? e1 : NEG, f2 = act ? e2 : NEG, f3 = act ? e3 : NEG;
        float m0 = wred_max(f0), m1 = wred_max(f1), m2 = wred_max(f2), m3 = wred_max(f3);
        float p0 = act ? __expf(e0 - m0) : 0.f;
        float p1 = act ? __expf(e1 - m1) : 0.f;
        float p2 = act ? __expf(e2 - m2) : 0.f;
        float p3 = act ? __expf(e3 - m3) : 0.f;
        float s0 = wred_sum(p0), s1 = wred_sum(p1), s2 = wred_sum(p2), s3 = wred_sum(p3);
        a4 = make_float4(act ? p0 / s0 : 0.f, act ? p1 / s1 : 0.f,
                         act ? p2 / s2 : 0.f, act ? p3 / s3 : 0.f);
    } else {
        a4 = make_float4(act ? __expf(e0 - mref.x) * vinv.x : 0.f,
                         act ? __expf(e1 - mref.y) * vinv.y : 0.f,
                         act ? __expf(e2 - mref.z) * vinv.z : 0.f,
                         act ? __expf(e3 - mref.w) * vinv.w : 0.f);
    }
    *reinterpret_cast<f32x2*>(&lalT[0 * LSTR + 2 * lane]) = (f32x2){a4.x, a4.x};
    *reinterpret_cast<f32x2*>(&lalT[1 * LSTR + 2 * lane]) = (f32x2){a4.y, a4.y};
    *reinterpret_cast<f32x2*>(&lalT[2 * LSTR + 2 * lane]) = (f32x2){a4.z, a4.z};
    *reinterpret_cast<f32x2*>(&lalT[3 * LSTR + 2 * lane]) = (f32x2){a4.w, a4.w};
    lsrc[lane] = srcn;
}

// global-stats pass for deg>64 nodes
__device__ __forceinline__ void stats_pass(const float* __restrict__ el,
                                           const int* __restrict__ csrc,
                                           float4 erv, int i0, int i1, int lane,
                                           float4& mout, float4& vout) {
    const float NEG = -__builtin_inff();
    float m0 = NEG, m1 = NEG, m2 = NEG, m3 = NEG;
    float s0 = 0.f, s1 = 0.f, s2 = 0.f, s3 = 0.f;
    for (int base = i0; base < i1; base += 64) {
        int i = base + lane;
        bool act = i < i1;
        int srcn = act ? csrc[i] : 0;
        float4 elv = make_float4(0.f, 0.f, 0.f, 0.f);
        if (act) elv = *reinterpret_cast<const float4*>(el + (size_t)srcn * NH);
        float e0 = elv.x + erv.x; e0 = e0 >= 0.f ? e0 : 0.2f * e0;
        float e1 = elv.y + erv.y; e1 = e1 >= 0.f ? e1 : 0.2f * e1;
        float e2 = elv.z + erv.z; e2 = e2 >= 0.f ? e2 : 0.2f * e2;
        float e3 = elv.w + erv.w; e3 = e3 >= 0.f ? e3 : 0.2f * e3;
        if (!act) { e0 = NEG; e1 = NEG; e2 = NEG; e3 = NEG; }
        float c0 = wred_max(e0), c1 = wred_max(e1), c2 = wred_max(e2), c3 = wred_max(e3);
        float nm0 = fmaxf(m0, c0), nm1 = fmaxf(m1, c1), nm2 = fmaxf(m2, c2), nm3 = fmaxf(m3, c3);
        float p0 = act ? __expf(e0 - nm0) : 0.f;
        float p1 = act ? __expf(e1 - nm1) : 0.f;
        float p2 = act ? __expf(e2 - nm2) : 0.f;
        float p3 = act ? __expf(e3 - nm3) : 0.f;
        float S0 = wred_sum(p0), S1 = wred_sum(p1), S2 = wred_sum(p2), S3 = wred_sum(p3);
        s0 = s0 * __expf(m0 - nm0) + S0; m0 = nm0;
        s1 = s1 * __expf(m1 - nm1) + S1; m1 = nm1;
        s2 = s2 * __expf(m2 - nm2) + S2; m2 = nm2;
        s3 = s3 * __expf(m3 - nm3) + S3; m3 = nm3;
    }
    mout = make_float4(m0, m1, m2, m3);
    vout = make_float4(1.f / s0, 1.f / s1, 1.f / s2, 1.f / s3);
}

// ---------------- fused softmax+aggregation, layers 1-2 (128 cols) ----------------
__global__ __launch_bounds__(256) void gat_agg128(const u16* __restrict__ feat,
                                                  const float* __restrict__ el,
                                                  const float* __restrict__ er,
                                                  const int* __restrict__ offs,
                                                  const int* __restrict__ csrc,
                                                  u16* __restrict__ out) {
    __shared__ float lalT[4][4][LSTR];
    __shared__ int lsrc[4][64];
    int wave = threadIdx.x >> 6;
    int lane = threadIdx.x & 63;
    int n = blockIdx.x * 4 + wave;
    int h = lane >> 4;
    int i0 = offs[n], i1 = offs[n + 1];
    int d = i1 - i0;
    f32x2 acc = (f32x2){0.f, 0.f};
    if (d > 0) {
        float4 erv = *reinterpret_cast<const float4*>(er + (size_t)n * NH);
        float4 mref = make_float4(0.f, 0.f, 0.f, 0.f), vinv = mref;
        bool onechunk = d <= 64;
        if (!onechunk) stats_pass(el, csrc, erv, i0, i1, lane, mref, vinv);
        for (int base = i0; base < i1; base += 64) {
            alpha_chunk_T(el, csrc, erv, base, i1, mref, vinv, onechunk,
                          &lalT[wave][0][0], &lsrc[wave][0], lane);
            int cnt = i1 - base; if (cnt > 64) cnt = 64;
            int cpad = (cnt + 3) & ~3;
            for (int j = 0; j < cpad; j += 4) {
                int4 sv = *reinterpret_cast<const int4*>(&lsrc[wave][j]);
                float4 q01 = *reinterpret_cast<const float4*>(&lalT[wave][h][2 * j]);
                float4 q23 = *reinterpret_cast<const float4*>(&lalT[wave][h][2 * j + 4]);
                u32 u0 = *reinterpret_cast<const u32*>(feat + (size_t)sv.x * 128 + 2 * lane);
                u32 u1 = *reinterpret_cast<const u32*>(feat + (size_t)sv.y * 128 + 2 * lane);
                u32 u2 = *reinterpret_cast<const u32*>(feat + (size_t)sv.z * 128 + 2 * lane);
                u32 u3 = *reinterpret_cast<const u32*>(feat + (size_t)sv.w * 128 + 2 * lane);
                f32x2 a0 = __builtin_shufflevector(*(const f32x4*)&q01, *(const f32x4*)&q01, 0, 1);
                f32x2 a1 = __builtin_shufflevector(*(const f32x4*)&q01, *(const f32x4*)&q01, 2, 3);
                f32x2 a2 = __builtin_shufflevector(*(const f32x4*)&q23, *(const f32x4*)&q23, 0, 1);
                f32x2 a3 = __builtin_shufflevector(*(const f32x4*)&q23, *(const f32x4*)&q23, 2, 3);
                pkfma(acc, a0, bf2_to_v2(u0));
                pkfma(acc, a1, bf2_to_v2(u1));
                pkfma(acc, a2, bf2_to_v2(u2));
                pkfma(acc, a3, bf2_to_v2(u3));
            }
        }
    }
    float ox = acc.x > 0.f ? acc.x : expm1f(acc.x);
    float oy = acc.y > 0.f ? acc.y : expm1f(acc.y);
    *reinterpret_cast<u32*>(out + (size_t)n * 128 + 2 * lane) = pack_bf2(ox, oy);
}

// ---------------- fused softmax+aggregation, layer 3 (192-col head-major-48) ----------------
__global__ __launch_bounds__(256) void gat_agg_final(const u16* __restrict__ feat,
                                                     const float* __restrict__ el,
                                                     const float* __restrict__ er,
                                                     const int* __restrict__ offs,
                                                     const int* __restrict__ csrc,
                                                     float* __restrict__ out) {
    __shared__ float lalT[4][4][LSTR];
    __shared__ int lsrc[4][64];
    __shared__ float lds[4][192];
    int wave = threadIdx.x >> 6;
    int lane = threadIdx.x & 63;
    int n = blockIdx.x * 4 + wave;
    int e0 = 2 * lane;
    bool up = lane < 32;
    int hLo = e0 / 48;                   // pairs never straddle heads (48 even)
    int hHi = up ? (128 + e0) / 48 : 3;
    int i0 = offs[n], i1 = offs[n + 1];
    int d = i1 - i0;
    f32x2 accLo = (f32x2){0.f, 0.f};
    f32x2 accHi = (f32x2){0.f, 0.f};
    if (d > 0) {
        float4 erv = *reinterpret_cast<const float4*>(er + (size_t)n * NH);
        float4 mref = make_float4(0.f, 0.f, 0.f, 0.f), vinv = mref;
        bool onechunk = d <= 64;
        if (!onechunk) stats_pass(el, csrc, erv, i0, i1, lane, mref, vinv);
        for (int base = i0; base < i1; base += 64) {
            alpha_chunk_T(el, csrc, erv, base, i1, mref, vinv, onechunk,
                          &lalT[wave][0][0], &lsrc[wave][0], lane);
            int cnt = i1 - base; if (cnt > 64) cnt = 64;
            int cpad = (cnt + 3) & ~3;
            for (int j = 0; j < cpad; j += 4) {
                int4 sv = *reinterpret_cast<const int4*>(&lsrc[wave][j]);
                float4 lo01 = *reinterpret_cast<const float4*>(&lalT[wave][hLo][2 * j]);
                float4 lo23 = *reinterpret_cast<const float4*>(&lalT[wave][hLo][2 * j + 4]);
                float4 hi01 = *reinterpret_cast<const float4*>(&lalT[wave][hHi][2 * j]);
                float4 hi23 = *reinterpret_cast<const float4*>(&lalT[wave][hHi][2 * j + 4]);
                const u16* rA = feat + (size_t)sv.x * 192;
                const u16* rB = feat + (size_t)sv.y * 192;
                const u16* rC = feat + (size_t)sv.z * 192;
                const u16* rD = feat + (size_t)sv.w * 192;
                u32 a0 = *reinterpret_cast<const u32*>(rA + e0);
                u32 b0 = *reinterpret_cast<const u32*>(rB + e0);
                u32 c0 = *reinterpret_cast<const u32*>(rC + e0);
                u32 d0 = *reinterpret_cast<const u32*>(rD + e0);
                u32 a1 = up ? *reinterpret_cast<const u32*>(rA + 128 + e0) : 0u;
                u32 b1 = up ? *reinterpret_cast<const u32*>(rB + 128 + e0) : 0u;
                u32 c1 = up ? *reinterpret_cast<const u32*>(rC + 128 + e0) : 0u;
                u32 d1 = up ? *reinterpret_cast<const u32*>(rD + 128 + e0) : 0u;
                f32x2 wA = __builtin_shufflevector(*(const f32x4*)&lo01, *(const f32x4*)&lo01, 0, 1);
                f32x2 wB = __builtin_shufflevector(*(const f32x4*)&lo01, *(const f32x4*)&lo01, 2, 3);
                f32x2 wC = __builtin_shufflevector(*(const f32x4*)&lo23, *(const f32x4*)&lo23, 0, 1);
                f32x2 wD = __builtin_shufflevector(*(const f32x4*)&lo23, *(const f32x4*)&lo23, 2, 3);
                pkfma(accLo, wA, bf2_to_v2(a0));
                pkfma(accLo, wB, bf2_to_v2(b0));
                pkfma(accLo, wC, bf2_to_v2(c0));
                pkfma(accLo, wD, bf2_to_v2(d0));
                f32x2 vA = __builtin_shufflevector(*(const f32x4*)&hi01, *(const f32x4*)&hi01, 0, 1);
                f32x2 vB = __builtin_shufflevector(*(const f32x4*)&hi01, *(const f32x4*)&hi01, 2, 3);
                f32x2 vC = __builtin_shufflevector(*(const f32x4*)&hi23, *(const f32x4*)&hi23, 0, 1);
                f32x2 vD = __builtin_shufflevector(*(const f32x4*)&hi23, *(const f32x4*)&hi23, 2, 3);
                pkfma(accHi, vA, bf2_to_v2(a1));
                pkfma(accHi, vB, bf2_to_v2(b1));
                pkfma(accHi, vC, bf2_to_v2(c1));
                pkfma(accHi, vD, bf2_to_v2(d1));
            }
        }
    }
    lds[wave][e0] = accLo.x;
    lds[wave][e0 + 1] = accLo.y;
    if (up) {
        lds[wave][128 + e0] = accHi.x;
        lds[wave][129 + e0] = accHi.y;
    }
    __syncthreads();
    float u = (lane < 47)
                  ? 0.25f * (lds[wave][lane] + lds[wave][48 + lane] +
                             lds[wave][96 + lane] + lds[wave][144 + lane])
                  : -__builtin_inff();
    float mx = u;
#pragma unroll
    for (int o = 32; o > 0; o >>= 1) mx = fmaxf(mx, __shfl_xor(mx, o));
    float ex = (lane < 47) ? __expf(u - mx) : 0.f;
    float sm = ex;
#pragma unroll
    for (int o = 32; o > 0; o >>= 1) sm += __shfl_xor(sm, o);
    if (lane < 47) out[(size_t)n * 47 + lane] = u - mx - logf(sm);
}

// ---------------- launch ----------------

extern "C" void kernel_launch(void* const* d_in, const int* in_sizes, int n_in,
                              void* d_out, int out_size, void* d_ws, size_t ws_size,
                              hipStream_t stream) {
    const float* x = (const float*)d_in[0];
    const int* src = (const int*)d_in[1];
    const int* dst = (const int*)d_in[2];
    const float* W1 = (const float*)d_in[3];
    const float* al1 = (const float*)d_in[4];
    const float* ar1 = (const float*)d_in[5];
    const float* W2 = (const float*)d_in[6];
    const float* al2 = (const float*)d_in[7];
    const float* ar2 = (const float*)d_in[8];
    const float* W3 = (const float*)d_in[9];
    const float* al3 = (const float*)d_in[10];
    const float* ar3 = (const float*)d_in[11];
    float* out = (float*)d_out;

    char* p = (char*)d_ws;
    auto alloc = [&](size_t bytes) {
        char* r = p;
        p += (bytes + 255) & ~(size_t)255;
        return r;
    };
    u16* bufA = (u16*)alloc((size_t)N_NODES * 128 * 2);
    u16* bufC = (u16*)alloc((size_t)N_NODES * 128 * 2);
    u16* featb = (u16*)alloc((size_t)N_NODES * 192 * 2);
    float* el = (float*)alloc((size_t)N_NODES * NH * 4);
    float* er = (float*)alloc((size_t)N_NODES * NH * 4);
    u16* wp1 = (u16*)alloc((size_t)32768 * 2);
    u16* wp2 = (u16*)alloc((size_t)16384 * 2);
    u16* wp3 = (u16*)alloc((size_t)24576 * 2);
    int* deg = (int*)alloc((size_t)N_NODES * 4);
    int* offs = (int*)alloc((size_t)(N_NODES + 1) * 4);
    int* cursor = (int*)alloc((size_t)N_NODES * 4);
    int* bsum = (int*)alloc(64 * 4);
    int* csrc = (int*)alloc((size_t)N_EDGES * 4);

    // fused W pre-pack (one dispatch)
    prep_all<<<288, 256, 0, stream>>>(W1, W2, W3, wp1, wp2, wp3);

    // CSR by dst
    hipMemsetAsync(deg, 0, (size_t)N_NODES * 4, stream);
    k_hist<<<(N_EDGES + 255) / 256, 256, 0, stream>>>(dst, deg);
    k_scan1<<<49, 1024, 0, stream>>>(deg, offs, bsum);
    k_scan2<<<1, 64, 0, stream>>>(bsum, 49);
    k_scan3<<<49, 1024, 0, stream>>>(offs, bsum, cursor);
    k_scatter<<<(N_EDGES + 255) / 256, 256, 0, stream>>>(src, dst, cursor, csrc);

    int gemm_grid = (N_NODES + 63) / 64;
    // layer 1
    gemm_mfma<256, 128, 128, true, true, false><<<gemm_grid, 256, 0, stream>>>(x, wp1, featb, al1, ar1, el, er);
    gat_agg128<<<N_NODES / 4, 256, 0, stream>>>(featb, el, er, offs, csrc, bufA);
    // layer 2
    gemm_mfma<128, 128, 128, false, true, false><<<gemm_grid, 256, 0, stream>>>(bufA, wp2, featb, al2, ar2, el, er);
    gat_agg128<<<N_NODES / 4, 256, 0, stream>>>(featb, el, er, offs, csrc, bufC);
    // layer 3 (head-major-48 padded layout; dots fused)
    gemm_mfma<128, 192, 192, false, true, true><<<gemm_grid, 256, 0, stream>>>(bufC, wp3, featb, al3, ar3, el, er);
    gat_agg_final<<<N_NODES / 4, 256, 0, stream>>>(featb, el, er, offs, csrc, out);
}

// Round 12
// 291.964 us; speedup vs baseline: 1.4429x; 1.0371x over previous
//
#include <hip/hip_runtime.h>
#include <hip/hip_bf16.h>
#include <math.h>
#include <string.h>

#define N_NODES 50000
#define N_EDGES 800000
#define NH 4
#define LSTR 68   // padded lalT stride (floats): head rows 272B apart -> banks 0/4/8/12

typedef unsigned int u32;
typedef unsigned short u16;
typedef __attribute__((ext_vector_type(8))) short bf16x8;
typedef __attribute__((ext_vector_type(4))) float f32x4;

__device__ __forceinline__ u32 pack_bf2(float a, float b) {
    __hip_bfloat162 h2 = __float22bfloat162_rn(make_float2(a, b));
    u32 r;
    memcpy(&r, &h2, 4);
    return r;
}
__device__ __forceinline__ float2 bf2_to_f2(u32 u) {
    return make_float2(__uint_as_float(u << 16), __uint_as_float(u & 0xffff0000u));
}
__device__ __forceinline__ short bf16r(float f) {
    __hip_bfloat16 h = __float2bfloat16(f);
    short s;
    memcpy(&s, &h, 2);
    return s;
}

__device__ __forceinline__ float wred_max(float v) {
#pragma unroll
    for (int o = 32; o > 0; o >>= 1) v = fmaxf(v, __shfl_xor(v, o));
    return v;
}
__device__ __forceinline__ float wred_sum(float v) {
#pragma unroll
    for (int o = 32; o > 0; o >>= 1) v += __shfl_xor(v, o);
    return v;
}

// ---------------- CSR build ----------------

__global__ void k_hist(const int* __restrict__ dst, int* __restrict__ deg) {
    int i = blockIdx.x * 256 + threadIdx.x;
    if (i < N_EDGES) atomicAdd(&deg[dst[i]], 1);
}

__global__ __launch_bounds__(1024) void k_scan1(const int* __restrict__ deg,
                                                int* __restrict__ offs,
                                                int* __restrict__ bsum) {
    __shared__ int tmp[1024];
    int b = blockIdx.x, t = threadIdx.x;
    int i = b * 1024 + t;
    int v = (i < N_NODES) ? deg[i] : 0;
    tmp[t] = v;
    __syncthreads();
    for (int off = 1; off < 1024; off <<= 1) {
        int add = (t >= off) ? tmp[t - off] : 0;
        __syncthreads();
        tmp[t] += add;
        __syncthreads();
    }
    if (i < N_NODES) offs[i] = tmp[t] - v;
    if (t == 1023) bsum[b] = tmp[t];
}

// wave-parallel exclusive scan of bsum (nb <= 64)
__global__ void k_scan2(int* __restrict__ bsum, int nb) {
    int t = threadIdx.x & 63;
    int v = (t < nb) ? bsum[t] : 0;
    int orig = v;
#pragma unroll
    for (int o = 1; o < 64; o <<= 1) {
        int u = __shfl_up(v, o);
        if (t >= o) v += u;
    }
    if (t < nb) bsum[t] = v - orig;
}

__global__ __launch_bounds__(1024) void k_scan3(int* __restrict__ offs,
                                                const int* __restrict__ bsum,
                                                int* __restrict__ cursor) {
    int b = blockIdx.x, t = threadIdx.x;
    int i = b * 1024 + t;
    if (i < N_NODES) {
        int o = offs[i] + bsum[b];
        offs[i] = o;
        cursor[i] = o;
    }
    if (b == 0 && t == 0) offs[N_NODES] = N_EDGES;
}

__global__ void k_scatter(const int* __restrict__ src, const int* __restrict__ dst,
                          int* __restrict__ cursor, int* __restrict__ csrc) {
    int i = blockIdx.x * 256 + threadIdx.x;
    if (i < N_EDGES) {
        int p = atomicAdd(&cursor[dst[i]], 1);
        csrc[p] = src[i];
    }
}

// ---------------- fused W pre-pack (all 3 layers, one dispatch) ----------------
__device__ __forceinline__ u16 pack_elem(const float* W, int i, int K, int NT, int NOUT) {
    int j = i & 7;
    int lane = (i >> 3) & 63;
    int rest = i >> 9;
    int nt = rest % NT;
    int kt = rest / NT;
    int k = kt * 32 + (lane >> 4) * 8 + j;
    int col = nt * 16 + (lane & 15);
    float v = (col < NOUT) ? W[(size_t)k * NOUT + col] : 0.f;
    return (u16)bf16r(v);
}
__device__ __forceinline__ u16 pack_elem3(const float* W, int i) {
    int j = i & 7;
    int lane = (i >> 3) & 63;
    int rest = i >> 9;
    int nt = rest % 12;
    int kt = rest / 12;
    int k = kt * 32 + (lane >> 4) * 8 + j;
    int col = nt * 16 + (lane & 15);
    int h = col / 48, d = col % 48;
    float v = (d < 47) ? W[(size_t)k * 188 + h * 47 + d] : 0.f;
    return (u16)bf16r(v);
}
__global__ void prep_all(const float* __restrict__ W1, const float* __restrict__ W2,
                         const float* __restrict__ W3, u16* __restrict__ wp1,
                         u16* __restrict__ wp2, u16* __restrict__ wp3) {
    int idx = blockIdx.x * 256 + threadIdx.x;
    if (idx < 32768) {
        wp1[idx] = pack_elem(W1, idx, 256, 8, 128);
    } else if (idx < 49152) {
        int i = idx - 32768;
        wp2[i] = pack_elem(W2, i, 128, 8, 128);
    } else if (idx < 73728) {
        int i = idx - 49152;
        wp3[i] = pack_elem3(W3, i);
    }
}

// ---------------- MFMA GEMM: feat(bf16,[N,NP]) = A @ W (+fused attn dots) ----------------
template <int K, int NOUT, int NP, bool AF32, bool DOTS, bool HEADPAD>
__global__ __launch_bounds__(256) void gemm_mfma(const void* __restrict__ Av,
                                                 const u16* __restrict__ Wp,
                                                 u16* __restrict__ feat,
                                                 const float* __restrict__ al,
                                                 const float* __restrict__ ar,
                                                 float* __restrict__ el,
                                                 float* __restrict__ er) {
    constexpr int NT = NP / 16;
    constexpr int KT = K / 32;
    int w = threadIdx.x >> 6, l = threadIdx.x & 63;
    int tile_m0 = blockIdx.x * 64 + w * 16;
    int c15 = l & 15;
    int rowA = tile_m0 + c15;
    if (rowA >= N_NODES) rowA = N_NODES - 1;
    int g = l >> 4;

    f32x4 acc[NT];
#pragma unroll
    for (int nt = 0; nt < NT; ++nt) acc[nt] = (f32x4){0.f, 0.f, 0.f, 0.f};

    for (int kt = 0; kt < KT; ++kt) {
        bf16x8 a;
        if constexpr (AF32) {
            const float* ap = (const float*)Av + (size_t)rowA * K + kt * 32 + g * 8;
            float4 f0 = *reinterpret_cast<const float4*>(ap);
            float4 f1 = *reinterpret_cast<const float4*>(ap + 4);
            a[0] = bf16r(f0.x); a[1] = bf16r(f0.y); a[2] = bf16r(f0.z); a[3] = bf16r(f0.w);
            a[4] = bf16r(f1.x); a[5] = bf16r(f1.y); a[6] = bf16r(f1.z); a[7] = bf16r(f1.w);
        } else {
            a = *reinterpret_cast<const bf16x8*>((const u16*)Av + (size_t)rowA * K + kt * 32 + g * 8);
        }
        const u16* wp = Wp + ((size_t)kt * NT) * 512 + (size_t)l * 8;
#pragma unroll
        for (int nt = 0; nt < NT; ++nt) {
            bf16x8 b = *reinterpret_cast<const bf16x8*>(wp + nt * 512);
            acc[nt] = __builtin_amdgcn_mfma_f32_16x16x32_bf16(a, b, acc[nt], 0, 0, 0);
        }
    }

    int rowD0 = tile_m0 + g * 4;
#pragma unroll
    for (int nt = 0; nt < NT; ++nt) {
        int col = nt * 16 + c15;
#pragma unroll
        for (int r = 0; r < 4; ++r) {
            int row = rowD0 + r;
            if (row < N_NODES)
                feat[(size_t)row * NP + col] = (u16)bf16r(acc[nt][r]);
        }
    }

    if constexpr (DOTS) {
        float alv[NT], arv[NT];
#pragma unroll
        for (int nt = 0; nt < NT; ++nt) {
            if constexpr (HEADPAD) {
                int h = nt / 3, m = nt % 3;
                if (m == 2) {
                    alv[nt] = (c15 < 15) ? al[h * 47 + 32 + c15] : 0.f;
                    arv[nt] = (c15 < 15) ? ar[h * 47 + 32 + c15] : 0.f;
                } else {
                    alv[nt] = al[h * 47 + m * 16 + c15];
                    arv[nt] = ar[h * 47 + m * 16 + c15];
                }
            } else {
                alv[nt] = al[nt * 16 + c15];
                arv[nt] = ar[nt * 16 + c15];
            }
        }
#pragma unroll
        for (int r = 0; r < 4; ++r) {
            float hlv[NH] = {0.f, 0.f, 0.f, 0.f};
            float hrv[NH] = {0.f, 0.f, 0.f, 0.f};
#pragma unroll
            for (int nt = 0; nt < NT; ++nt) {
                constexpr int NTH = NT / NH;
                int h = nt / NTH;
                hlv[h] = fmaf(acc[nt][r], alv[nt], hlv[h]);
                hrv[h] = fmaf(acc[nt][r], arv[nt], hrv[h]);
            }
#pragma unroll
            for (int o = 1; o < 16; o <<= 1) {
#pragma unroll
                for (int j = 0; j < NH; ++j) {
                    hlv[j] += __shfl_xor(hlv[j], o);
                    hrv[j] += __shfl_xor(hrv[j], o);
                }
            }
            int row = rowD0 + r;
            if (c15 == 0 && row < N_NODES) {
                *reinterpret_cast<float4*>(el + (size_t)row * NH) =
                    make_float4(hlv[0], hlv[1], hlv[2], hlv[3]);
                *reinterpret_cast<float4*>(er + (size_t)row * NH) =
                    make_float4(hrv[0], hrv[1], hrv[2], hrv[3]);
            }
        }
    }
}

// ---------------- per-chunk alpha -> LDS (transposed, scalar, padded stride) ----------------
__device__ __forceinline__ void alpha_chunk_T(const float* __restrict__ el,
                                              const int* __restrict__ csrc,
                                              float4 erv, int base, int i1,
                                              float4 mref, float4 vinv, bool online,
                                              float* __restrict__ lalT,
                                              int* __restrict__ lsrc, int lane) {
    int e = base + lane;
    bool act = e < i1;
    int srcn = act ? csrc[e] : 0;
    float4 elv = make_float4(0.f, 0.f, 0.f, 0.f);
    if (act) elv = *reinterpret_cast<const float4*>(el + (size_t)srcn * NH);
    float e0 = elv.x + erv.x; e0 = e0 >= 0.f ? e0 : 0.2f * e0;
    float e1 = elv.y + erv.y; e1 = e1 >= 0.f ? e1 : 0.2f * e1;
    float e2 = elv.z + erv.z; e2 = e2 >= 0.f ? e2 : 0.2f * e2;
    float e3 = elv.w + erv.w; e3 = e3 >= 0.f ? e3 : 0.2f * e3;
    float4 a4;
    if (online) {
        const float NEG = -__builtin_inff();
        float f0 = act ? e0 : NEG, f1 = act ? e1 : NEG, f2 = act ? e2 : NEG, f3 = act ? e3 : NEG;
        float m0 = wred_max(f0), m1 = wred_max(f1), m2 = wred_max(f2), m3 = wred_max(f3);
        float p0 = act ? __expf(e0 - m0) : 0.f;
        float p1 = act ? __expf(e1 - m1) : 0.f;
        float p2 = act ? __expf(e2 - m2) : 0.f;
        float p3 = act ? __expf(e3 - m3) : 0.f;
        float s0 = wred_sum(p0), s1 = wred_sum(p1), s2 = wred_sum(p2), s3 = wred_sum(p3);
        a4 = make_float4(act ? p0 / s0 : 0.f, act ? p1 / s1 : 0.f,
                         act ? p2 / s2 : 0.f, act ? p3 / s3 : 0.f);
    } else {
        a4 = make_float4(act ? __expf(e0 - mref.x) * vinv.x : 0.f,
                         act ? __expf(e1 - mref.y) * vinv.y : 0.f,
                         act ? __expf(e2 - mref.z) * vinv.z : 0.f,
                         act ? __expf(e3 - mref.w) * vinv.w : 0.f);
    }
    lalT[0 * LSTR + lane] = a4.x;
    lalT[1 * LSTR + lane] = a4.y;
    lalT[2 * LSTR + lane] = a4.z;
    lalT[3 * LSTR + lane] = a4.w;
    lsrc[lane] = srcn;
}

// global-stats pass for deg>64 nodes
__device__ __forceinline__ void stats_pass(const float* __restrict__ el,
                                           const int* __restrict__ csrc,
                                           float4 erv, int i0, int i1, int lane,
                                           float4& mout, float4& vout) {
    const float NEG = -__builtin_inff();
    float m0 = NEG, m1 = NEG, m2 = NEG, m3 = NEG;
    float s0 = 0.f, s1 = 0.f, s2 = 0.f, s3 = 0.f;
    for (int base = i0; base < i1; base += 64) {
        int i = base + lane;
        bool act = i < i1;
        int srcn = act ? csrc[i] : 0;
        float4 elv = make_float4(0.f, 0.f, 0.f, 0.f);
        if (act) elv = *reinterpret_cast<const float4*>(el + (size_t)srcn * NH);
        float e0 = elv.x + erv.x; e0 = e0 >= 0.f ? e0 : 0.2f * e0;
        float e1 = elv.y + erv.y; e1 = e1 >= 0.f ? e1 : 0.2f * e1;
        float e2 = elv.z + erv.z; e2 = e2 >= 0.f ? e2 : 0.2f * e2;
        float e3 = elv.w + erv.w; e3 = e3 >= 0.f ? e3 : 0.2f * e3;
        if (!act) { e0 = NEG; e1 = NEG; e2 = NEG; e3 = NEG; }
        float c0 = wred_max(e0), c1 = wred_max(e1), c2 = wred_max(e2), c3 = wred_max(e3);
        float nm0 = fmaxf(m0, c0), nm1 = fmaxf(m1, c1), nm2 = fmaxf(m2, c2), nm3 = fmaxf(m3, c3);
        float p0 = act ? __expf(e0 - nm0) : 0.f;
        float p1 = act ? __expf(e1 - nm1) : 0.f;
        float p2 = act ? __expf(e2 - nm2) : 0.f;
        float p3 = act ? __expf(e3 - nm3) : 0.f;
        float S0 = wred_sum(p0), S1 = wred_sum(p1), S2 = wred_sum(p2), S3 = wred_sum(p3);
        s0 = s0 * __expf(m0 - nm0) + S0; m0 = nm0;
        s1 = s1 * __expf(m1 - nm1) + S1; m1 = nm1;
        s2 = s2 * __expf(m2 - nm2) + S2; m2 = nm2;
        s3 = s3 * __expf(m3 - nm3) + S3; m3 = nm3;
    }
    mout = make_float4(m0, m1, m2, m3);
    vout = make_float4(1.f / s0, 1.f / s1, 1.f / s2, 1.f / s3);
}

// ---------------- fused softmax+aggregation, layers 1-2 (128 cols) ----------------
__global__ __launch_bounds__(256) void gat_agg128(const u16* __restrict__ feat,
                                                  const float* __restrict__ el,
                                                  const float* __restrict__ er,
                                                  const int* __restrict__ offs,
                                                  const int* __restrict__ csrc,
                                                  u16* __restrict__ out) {
    __shared__ float lalT[4][4][LSTR];
    __shared__ int lsrc[4][64];
    int wave = threadIdx.x >> 6;
    int lane = threadIdx.x & 63;
    int n = blockIdx.x * 4 + wave;
    int h = lane >> 4;
    u32 lo4 = (u32)lane * 4u;   // per-lane byte offset within row
    int i0 = offs[n], i1 = offs[n + 1];
    int d = i1 - i0;
    float ax = 0.f, ay = 0.f;
    if (d > 0) {
        float4 erv = *reinterpret_cast<const float4*>(er + (size_t)n * NH);
        float4 mref = make_float4(0.f, 0.f, 0.f, 0.f), vinv = mref;
        bool onechunk = d <= 64;
        if (!onechunk) stats_pass(el, csrc, erv, i0, i1, lane, mref, vinv);
        const char* fbase = (const char*)feat;
        for (int base = i0; base < i1; base += 64) {
            alpha_chunk_T(el, csrc, erv, base, i1, mref, vinv, onechunk,
                          &lalT[wave][0][0], &lsrc[wave][0], lane);
            int cnt = i1 - base; if (cnt > 64) cnt = 64;
            int cpad = (cnt + 3) & ~3;
            for (int j = 0; j < cpad; j += 4) {
                int4 sv = *reinterpret_cast<const int4*>(&lsrc[wave][j]);
                float4 aq = *reinterpret_cast<const float4*>(&lalT[wave][h][j]);
                u32 o0 = ((u32)sv.x << 8) + lo4;   // row*256 + lane*4 bytes
                u32 o1 = ((u32)sv.y << 8) + lo4;
                u32 o2 = ((u32)sv.z << 8) + lo4;
                u32 o3 = ((u32)sv.w << 8) + lo4;
                u32 q0 = *reinterpret_cast<const u32*>(fbase + o0);
                u32 q1 = *reinterpret_cast<const u32*>(fbase + o1);
                u32 q2 = *reinterpret_cast<const u32*>(fbase + o2);
                u32 q3 = *reinterpret_cast<const u32*>(fbase + o3);
                float2 v;
                v = bf2_to_f2(q0); ax = fmaf(aq.x, v.x, ax); ay = fmaf(aq.x, v.y, ay);
                v = bf2_to_f2(q1); ax = fmaf(aq.y, v.x, ax); ay = fmaf(aq.y, v.y, ay);
                v = bf2_to_f2(q2); ax = fmaf(aq.z, v.x, ax); ay = fmaf(aq.z, v.y, ay);
                v = bf2_to_f2(q3); ax = fmaf(aq.w, v.x, ax); ay = fmaf(aq.w, v.y, ay);
            }
        }
    }
    float ox = ax > 0.f ? ax : expm1f(ax);
    float oy = ay > 0.f ? ay : expm1f(ay);
    *reinterpret_cast<u32*>(out + (size_t)n * 128 + 2 * lane) = pack_bf2(ox, oy);
}

// ---------------- fused softmax+aggregation, layer 3 (192-col head-major-48) ----------------
__global__ __launch_bounds__(256) void gat_agg_final(const u16* __restrict__ feat,
                                                     const float* __restrict__ el,
                                                     const float* __restrict__ er,
                                                     const int* __restrict__ offs,
                                                     const int* __restrict__ csrc,
                                                     float* __restrict__ out) {
    __shared__ float lalT[4][4][LSTR];
    __shared__ int lsrc[4][64];
    __shared__ float lds[4][192];
    int wave = threadIdx.x >> 6;
    int lane = threadIdx.x & 63;
    int n = blockIdx.x * 4 + wave;
    int e0 = 2 * lane;
    bool up = lane < 32;
    int hLo = e0 / 48;                   // pairs never straddle heads (48 even)
    int hHi = up ? (128 + e0) / 48 : 3;
    u32 lo4 = (u32)lane * 4u;
    int i0 = offs[n], i1 = offs[n + 1];
    int d = i1 - i0;
    float a00 = 0.f, a01 = 0.f, a10 = 0.f, a11 = 0.f;
    if (d > 0) {
        float4 erv = *reinterpret_cast<const float4*>(er + (size_t)n * NH);
        float4 mref = make_float4(0.f, 0.f, 0.f, 0.f), vinv = mref;
        bool onechunk = d <= 64;
        if (!onechunk) stats_pass(el, csrc, erv, i0, i1, lane, mref, vinv);
        const char* fbase = (const char*)feat;
        for (int base = i0; base < i1; base += 64) {
            alpha_chunk_T(el, csrc, erv, base, i1, mref, vinv, onechunk,
                          &lalT[wave][0][0], &lsrc[wave][0], lane);
            int cnt = i1 - base; if (cnt > 64) cnt = 64;
            int cpad = (cnt + 3) & ~3;
            for (int j = 0; j < cpad; j += 4) {
                int4 sv = *reinterpret_cast<const int4*>(&lsrc[wave][j]);
                float4 wlo = *reinterpret_cast<const float4*>(&lalT[wave][hLo][j]);
                float4 whi = *reinterpret_cast<const float4*>(&lalT[wave][hHi][j]);
                u32 oA = (u32)sv.x * 384u + lo4;   // row*384 + lane*4 bytes
                u32 oB = (u32)sv.y * 384u + lo4;
                u32 oC = (u32)sv.z * 384u + lo4;
                u32 oD = (u32)sv.w * 384u + lo4;
                u32 a0 = *reinterpret_cast<const u32*>(fbase + oA);
                u32 b0 = *reinterpret_cast<const u32*>(fbase + oB);
                u32 c0 = *reinterpret_cast<const u32*>(fbase + oC);
                u32 d0 = *reinterpret_cast<const u32*>(fbase + oD);
                u32 a1 = up ? *reinterpret_cast<const u32*>(fbase + oA + 256) : 0u;
                u32 b1 = up ? *reinterpret_cast<const u32*>(fbase + oB + 256) : 0u;
                u32 c1 = up ? *reinterpret_cast<const u32*>(fbase + oC + 256) : 0u;
                u32 d1 = up ? *reinterpret_cast<const u32*>(fbase + oD + 256) : 0u;
                float2 v;
                v = bf2_to_f2(a0); a00 = fmaf(wlo.x, v.x, a00); a01 = fmaf(wlo.x, v.y, a01);
                v = bf2_to_f2(b0); a00 = fmaf(wlo.y, v.x, a00); a01 = fmaf(wlo.y, v.y, a01);
                v = bf2_to_f2(c0); a00 = fmaf(wlo.z, v.x, a00); a01 = fmaf(wlo.z, v.y, a01);
                v = bf2_to_f2(d0); a00 = fmaf(wlo.w, v.x, a00); a01 = fmaf(wlo.w, v.y, a01);
                v = bf2_to_f2(a1); a10 = fmaf(whi.x, v.x, a10); a11 = fmaf(whi.x, v.y, a11);
                v = bf2_to_f2(b1); a10 = fmaf(whi.y, v.x, a10); a11 = fmaf(whi.y, v.y, a11);
                v = bf2_to_f2(c1); a10 = fmaf(whi.z, v.x, a10); a11 = fmaf(whi.z, v.y, a11);
                v = bf2_to_f2(d1); a10 = fmaf(whi.w, v.x, a10); a11 = fmaf(whi.w, v.y, a11);
            }
        }
    }
    lds[wave][e0] = a00;
    lds[wave][e0 + 1] = a01;
    if (up) {
        lds[wave][128 + e0] = a10;
        lds[wave][129 + e0] = a11;
    }
    __syncthreads();
    float u = (lane < 47)
                  ? 0.25f * (lds[wave][lane] + lds[wave][48 + lane] +
                             lds[wave][96 + lane] + lds[wave][144 + lane])
                  : -__builtin_inff();
    float mx = u;
#pragma unroll
    for (int o = 32; o > 0; o >>= 1) mx = fmaxf(mx, __shfl_xor(mx, o));
    float ex = (lane < 47) ? __expf(u - mx) : 0.f;
    float sm = ex;
#pragma unroll
    for (int o = 32; o > 0; o >>= 1) sm += __shfl_xor(sm, o);
    if (lane < 47) out[(size_t)n * 47 + lane] = u - mx - logf(sm);
}

// ---------------- launch ----------------

extern "C" void kernel_launch(void* const* d_in, const int* in_sizes, int n_in,
                              void* d_out, int out_size, void* d_ws, size_t ws_size,
                              hipStream_t stream) {
    const float* x = (const float*)d_in[0];
    const int* src = (const int*)d_in[1];
    const int* dst = (const int*)d_in[2];
    const float* W1 = (const float*)d_in[3];
    const float* al1 = (const float*)d_in[4];
    const float* ar1 = (const float*)d_in[5];
    const float* W2 = (const float*)d_in[6];
    const float* al2 = (const float*)d_in[7];
    const float* ar2 = (const float*)d_in[8];
    const float* W3 = (const float*)d_in[9];
    const float* al3 = (const float*)d_in[10];
    const float* ar3 = (const float*)d_in[11];
    float* out = (float*)d_out;

    char* p = (char*)d_ws;
    auto alloc = [&](size_t bytes) {
        char* r = p;
        p += (bytes + 255) & ~(size_t)255;
        return r;
    };
    u16* bufA = (u16*)alloc((size_t)N_NODES * 128 * 2);
    u16* bufC = (u16*)alloc((size_t)N_NODES * 128 * 2);
    u16* featb = (u16*)alloc((size_t)N_NODES * 192 * 2);
    float* el = (float*)alloc((size_t)N_NODES * NH * 4);
    float* er = (float*)alloc((size_t)N_NODES * NH * 4);
    u16* wp1 = (u16*)alloc((size_t)32768 * 2);
    u16* wp2 = (u16*)alloc((size_t)16384 * 2);
    u16* wp3 = (u16*)alloc((size_t)24576 * 2);
    int* deg = (int*)alloc((size_t)N_NODES * 4);
    int* offs = (int*)alloc((size_t)(N_NODES + 1) * 4);
    int* cursor = (int*)alloc((size_t)N_NODES * 4);
    int* bsum = (int*)alloc(64 * 4);
    int* csrc = (int*)alloc((size_t)N_EDGES * 4);

    // fused W pre-pack (one dispatch)
    prep_all<<<288, 256, 0, stream>>>(W1, W2, W3, wp1, wp2, wp3);

    // CSR by dst
    hipMemsetAsync(deg, 0, (size_t)N_NODES * 4, stream);
    k_hist<<<(N_EDGES + 255) / 256, 256, 0, stream>>>(dst, deg);
    k_scan1<<<49, 1024, 0, stream>>>(deg, offs, bsum);
    k_scan2<<<1, 64, 0, stream>>>(bsum, 49);
    k_scan3<<<49, 1024, 0, stream>>>(offs, bsum, cursor);
    k_scatter<<<(N_EDGES + 255) / 256, 256, 0, stream>>>(src, dst, cursor, csrc);

    int gemm_grid = (N_NODES + 63) / 64;
    // layer 1
    gemm_mfma<256, 128, 128, true, true, false><<<gemm_grid, 256, 0, stream>>>(x, wp1, featb, al1, ar1, el, er);
    gat_agg128<<<N_NODES / 4, 256, 0, stream>>>(featb, el, er, offs, csrc, bufA);
    // layer 2
    gemm_mfma<128, 128, 128, false, true, false><<<gemm_grid, 256, 0, stream>>>(bufA, wp2, featb, al2, ar2, el, er);
    gat_agg128<<<N_NODES / 4, 256, 0, stream>>>(featb, el, er, offs, csrc, bufC);
    // layer 3 (head-major-48 padded layout; dots fused)
    gemm_mfma<128, 192, 192, false, true, true><<<gemm_grid, 256, 0, stream>>>(bufC, wp3, featb, al3, ar3, el, er);
    gat_agg_final<<<N_NODES / 4, 256, 0, stream>>>(featb, el, er, offs, csrc, out);
}